// Round 15
// baseline (1029.914 us; speedup 1.0000x reference)
//
#include <hip/hip_runtime.h>
#include <math.h>

#define NL 6
#define NH 12
#define NE 768
#define NHS 64
#define NT 1024
#define NB 2
#define NV 32000
#define NM (NB * NT)   // 2048
#define NQKV (3 * NE)  // 2304
#define NFF (4 * NE)   // 3072
#define LN_EPS 1e-5f

typedef __attribute__((ext_vector_type(8))) short short8;
typedef __attribute__((ext_vector_type(4))) float f32x4;
typedef __attribute__((ext_vector_type(4))) unsigned short ushort4v;
typedef __attribute__((address_space(1))) const unsigned int as1_cuint;
typedef __attribute__((address_space(3))) unsigned int as3_uint;

__device__ __forceinline__ unsigned short f2bf(float f) {
    unsigned int u = __builtin_bit_cast(unsigned int, f);
    u += 0x7fffu + ((u >> 16) & 1u);   // RNE
    return (unsigned short)(u >> 16);
}
__device__ __forceinline__ float bf2f(unsigned short u) {
    unsigned int v = ((unsigned int)u) << 16;
    return __builtin_bit_cast(float, v);
}
__device__ __forceinline__ void gload_lds16(const void* g, void* l) {
    __builtin_amdgcn_global_load_lds((as1_cuint*)g, (as3_uint*)l, 16, 0, 0);
}

// ---------------- embedding + LN1(layer0) fused: one block per row ----------------
__global__ __launch_bounds__(256) void embed_ln_kernel(const int* __restrict__ idx,
                                                       const float* __restrict__ tok,
                                                       const float* __restrict__ pos,
                                                       const float* __restrict__ g,
                                                       const float* __restrict__ b,
                                                       float* __restrict__ x,
                                                       unsigned short* __restrict__ hbuf) {
    __shared__ float red[256];
    int row = blockIdx.x, tid = threadIdx.x;
    int t = row % NT;
    int id = idx[row];
    float v[3]; float s = 0.f;
    #pragma unroll
    for (int k = 0; k < 3; ++k) {
        int c = tid + k * 256;
        v[k] = tok[(long)id * NE + c] + pos[(long)t * NE + c];
        x[(long)row * NE + c] = v[k];
        s += v[k];
    }
    red[tid] = s; __syncthreads();
    for (int o = 128; o > 0; o >>= 1) { if (tid < o) red[tid] += red[tid + o]; __syncthreads(); }
    float mu = red[0] / NE;
    __syncthreads();
    float vr = 0.f;
    #pragma unroll
    for (int k = 0; k < 3; ++k) { float d = v[k] - mu; vr += d * d; }
    red[tid] = vr; __syncthreads();
    for (int o = 128; o > 0; o >>= 1) { if (tid < o) red[tid] += red[tid + o]; __syncthreads(); }
    float rstd = rsqrtf(red[0] / NE + LN_EPS);
    #pragma unroll
    for (int k = 0; k < 3; ++k) {
        int c = tid + k * 256;
        hbuf[(long)row * NE + c] = f2bf((v[k] - mu) * rstd * g[c] + b[c]);
    }
}

// ---------------- fused split-K combine (bf16 parts) + residual + LayerNorm ----------------
template<int S>
__global__ __launch_bounds__(256) void combine_ln_kernel(const unsigned short* __restrict__ parts,
                                                         const float* __restrict__ bias,
                                                         float* __restrict__ x,
                                                         const float* __restrict__ g,
                                                         const float* __restrict__ b,
                                                         unsigned short* __restrict__ hbuf) {
    __shared__ float red[256];
    int row = blockIdx.x, tid = threadIdx.x;
    float v[3]; float s = 0.f;
    #pragma unroll
    for (int k = 0; k < 3; ++k) {
        int c = tid + k * 256;
        long i = (long)row * NE + c;
        float a = bf2f(parts[i]);
        #pragma unroll
        for (int si = 1; si < S; ++si) a += bf2f(parts[(long)si * NM * NE + i]);
        a += bias[c] + x[i];
        x[i] = a;
        v[k] = a; s += a;
    }
    red[tid] = s; __syncthreads();
    for (int o = 128; o > 0; o >>= 1) { if (tid < o) red[tid] += red[tid + o]; __syncthreads(); }
    float mu = red[0] / NE;
    __syncthreads();
    float vr = 0.f;
    #pragma unroll
    for (int k = 0; k < 3; ++k) { float d = v[k] - mu; vr += d * d; }
    red[tid] = vr; __syncthreads();
    for (int o = 128; o > 0; o >>= 1) { if (tid < o) red[tid] += red[tid + o]; __syncthreads(); }
    float rstd = rsqrtf(red[0] / NE + LN_EPS);
    #pragma unroll
    for (int k = 0; k < 3; ++k) {
        int c = tid + k * 256;
        hbuf[(long)row * NE + c] = f2bf((v[k] - mu) * rstd * g[c] + b[c]);
    }
}

// ---------------- batched transpose of the four 768x768 weights (+ straight cast of wproj) ----------------
__global__ __launch_bounds__(256) void transpose4b_kernel(const float* __restrict__ wq,
                                                          const float* __restrict__ wk,
                                                          const float* __restrict__ wv,
                                                          const float* __restrict__ wp,
                                                          unsigned short* __restrict__ wqkvT,
                                                          unsigned short* __restrict__ wprojT,
                                                          unsigned short* __restrict__ wprojC) {
    __shared__ float t[32][33];
    int z = blockIdx.z, l = z >> 2, which = z & 3;
    const float* W = ((which == 0) ? wq : (which == 1) ? wk : (which == 2) ? wv : wp) + (long)l * NE * NE;
    unsigned short* WT = (which < 3) ? (wqkvT + (long)l * NQKV * NE + (long)which * NE * NE)
                                     : (wprojT + (long)l * NE * NE);
    int k0 = blockIdx.y * 32, n0 = blockIdx.x * 32;
    int c = threadIdx.x & 31, r = threadIdx.x >> 5;
    #pragma unroll
    for (int p = 0; p < 4; ++p)
        t[r + p * 8][c] = W[(long)(k0 + r + p * 8) * NE + n0 + c];
    __syncthreads();
    #pragma unroll
    for (int p = 0; p < 4; ++p)
        WT[(long)(n0 + r + p * 8) * NE + k0 + c] = f2bf(t[c][r + p * 8]);
    if (which == 3) {   // also emit non-transposed bf16 copy (B-operand for weff GEMM)
        unsigned short* WC = wprojC + (long)l * NE * NE;
        #pragma unroll
        for (int p = 0; p < 4; ++p)
            WC[(long)(k0 + r + p * 8) * NE + n0 + c] = f2bf(t[r + p * 8][c]);
    }
}

// ---------------- merged w1/w2 transpose: z<NL -> w1 [NE][NFF], else w2 [NFF][NE] ----------------
__global__ __launch_bounds__(256) void transpose_ffn_kernel(const float* __restrict__ w1,
                                                            const float* __restrict__ w2,
                                                            unsigned short* __restrict__ w1T,
                                                            unsigned short* __restrict__ w2T) {
    __shared__ float t[32][33];
    int z = blockIdx.z;
    bool isW1 = z < NL;
    int l = isW1 ? z : z - NL;
    const float* W = (isW1 ? w1 : w2) + (long)l * NE * NFF;
    unsigned short* WT = (isW1 ? w1T : w2T) + (long)l * NE * NFF;
    int K = isW1 ? NE : NFF, N = isW1 ? NFF : NE;
    // grid (96,24): w1 uses x as N-tiles(96), y as K-tiles(24); w2 swaps.
    int k0 = (isW1 ? blockIdx.y : blockIdx.x) * 32;
    int n0 = (isW1 ? blockIdx.x : blockIdx.y) * 32;
    int c = threadIdx.x & 31, r = threadIdx.x >> 5;
    #pragma unroll
    for (int p = 0; p < 4; ++p)
        t[r + p * 8][c] = W[(long)(k0 + r + p * 8) * N + n0 + c];
    __syncthreads();
    #pragma unroll
    for (int p = 0; p < 4; ++p)
        WT[(long)(n0 + r + p * 8) * K + k0 + c] = f2bf(t[c][r + p * 8]);
}

// ---------------- tiled transpose + cast (lm head) ----------------
__global__ __launch_bounds__(256) void transpose_cast_kernel(const float* __restrict__ W,
                                                             unsigned short* __restrict__ WT,
                                                             int K, int N) {
    __shared__ float t[32][33];
    int k0 = blockIdx.y * 32, n0 = blockIdx.x * 32;
    int c = threadIdx.x & 31, r = threadIdx.x >> 5;
    #pragma unroll
    for (int p = 0; p < 4; ++p)
        t[r + p * 8][c] = W[(long)(k0 + r + p * 8) * N + n0 + c];
    __syncthreads();
    #pragma unroll
    for (int p = 0; p < 4; ++p)
        WT[(long)(n0 + r + p * 8) * K + k0 + c] = f2bf(t[c][r + p * 8]);
}

// ---------------- batched beff ----------------
__global__ __launch_bounds__(256) void beff_b_kernel(const float* __restrict__ bproj,
                                                     const unsigned short* __restrict__ wprojT,
                                                     float* __restrict__ beff) {
    __shared__ float red[256];
    int n = blockIdx.x, l = blockIdx.y, tid = threadIdx.x;
    const unsigned short* wp = wprojT + (long)l * NE * NE + (long)n * NE;
    const float* bp = bproj + (long)l * NE;
    float acc = 0.f;
    for (int j = tid; j < NE; j += 256) acc += bp[j] * bf2f(wp[j]);
    red[tid] = acc; __syncthreads();
    for (int o = 128; o > 0; o >>= 1) { if (tid < o) red[tid] += red[tid + o]; __syncthreads(); }
    if (tid == 0) beff[(long)l * NE + n] = red[0] + bp[n];
}

// ---------------- 128x128 bf16 MFMA GEMM: 3-slot ring, depth-2 counted vmcnt ----------------
// SPLITK>1: writes bf16 partials. VTRANS: V-columns (>=2*NE) also emitted transposed to vt.
template<typename OutT, bool BIAS, bool RELU, int SPLITK, bool VTRANS>
__global__ __launch_bounds__(256) void gemm_mfma(const unsigned short* __restrict__ A,
                                                 const unsigned short* __restrict__ BT,
                                                 const float* __restrict__ bias,
                                                 OutT* __restrict__ C,
                                                 unsigned short* __restrict__ vt,
                                                 int gridM, int N, int K) {
    __shared__ unsigned short As[3][128 * 32];
    __shared__ unsigned short Bs[3][128 * 32];
    int tid = threadIdx.x;
    int lane = tid & 63, w = tid >> 6;
    int wr = w >> 1, wc = w & 1;
    int l4 = lane >> 4, l15 = lane & 15;

    int nwg = gridDim.x, orig = blockIdx.x;
    int q = nwg >> 3, r8 = nwg & 7;
    int xcd = orig & 7, ii = orig >> 3;
    int wg = (xcd < r8) ? (xcd * (q + 1) + ii) : (r8 * (q + 1) + (xcd - r8) * q + ii);
    int bm = wg % gridM, bn = wg / gridM;
    int m0 = bm * 128, n0 = bn * 128;

    int kb = K / SPLITK;
    int koff = (SPLITK > 1) ? blockIdx.y * kb : 0;
    int nkt = kb >> 5;

    f32x4 acc[4][4] = {};

    int srow = lane >> 2;
    int scol = ((lane & 3) ^ ((lane >> 3) & 3)) * 8;   // inverse-swizzled source slot
    int rsw  = (l4 ^ ((l15 >> 1) & 3)) * 8;            // swizzled read slot

    auto STAGE = [&](int slot, int kt) {   // 4 gload_lds per wave
        #pragma unroll
        for (int it = 0; it < 2; ++it) {
            int rr = w * 32 + it * 16;
            gload_lds16(&A [(long)(m0 + rr + srow) * K + koff + kt * 32 + scol], &As[slot][rr * 32]);
            gload_lds16(&BT[(long)(n0 + rr + srow) * K + koff + kt * 32 + scol], &Bs[slot][rr * 32]);
        }
    };

    STAGE(0, 0);
    if (nkt > 1) STAGE(1, 1);

    int s = 0;
    for (int t = 0; t < nkt; ++t) {
        if (t + 2 < nkt) STAGE((t + 2) % 3, t + 2);
        int ahead = nkt - 1 - t;
        if (ahead >= 2)      asm volatile("s_waitcnt vmcnt(8)" ::: "memory");
        else if (ahead == 1) asm volatile("s_waitcnt vmcnt(4)" ::: "memory");
        else                 asm volatile("s_waitcnt vmcnt(0)" ::: "memory");
        asm volatile("s_barrier" ::: "memory");        // slot s fully staged for all waves

        short8 a[4], b[4];
        #pragma unroll
        for (int f = 0; f < 4; ++f) {
            a[f] = *(const short8*)&As[s][(wr * 64 + f * 16 + l15) * 32 + rsw];
            b[f] = *(const short8*)&Bs[s][(wc * 64 + f * 16 + l15) * 32 + rsw];
        }
        asm volatile("s_waitcnt lgkmcnt(0)" ::: "memory");
        asm volatile("s_barrier" ::: "memory");        // all reads of slot s done -> restageable

        __builtin_amdgcn_s_setprio(1);
        #pragma unroll
        for (int fm = 0; fm < 4; ++fm)
            #pragma unroll
            for (int fn = 0; fn < 4; ++fn)
                acc[fm][fn] = __builtin_amdgcn_mfma_f32_16x16x32_bf16(a[fm], b[fn], acc[fm][fn], 0, 0, 0);
        __builtin_amdgcn_s_setprio(0);
        s = (s + 1) % 3;
    }

    if constexpr (SPLITK > 1) {
        unsigned short* Cp = (unsigned short*)C + (long)blockIdx.y * gridM * 128 * N;
        #pragma unroll
        for (int fm = 0; fm < 4; ++fm)
            #pragma unroll
            for (int j = 0; j < 4; ++j) {
                long row = m0 + wr * 64 + fm * 16 + l4 * 4 + j;
                #pragma unroll
                for (int fn = 0; fn < 4; ++fn)
                    Cp[row * N + n0 + wc * 64 + fn * 16 + l15] = f2bf(acc[fm][fn][j]);
            }
    } else {
        float bs[4];
        #pragma unroll
        for (int fn = 0; fn < 4; ++fn)
            bs[fn] = BIAS ? bias[n0 + wc * 64 + fn * 16 + l15] : 0.f;

        #pragma unroll
        for (int fm = 0; fm < 4; ++fm) {
            #pragma unroll
            for (int fn = 0; fn < 4; ++fn) {
                int col = n0 + wc * 64 + fn * 16 + l15;
                long t0 = m0 + wr * 64 + fm * 16 + l4 * 4;
                ushort4v pk;
                #pragma unroll
                for (int j = 0; j < 4; ++j) {
                    long row = t0 + j;
                    float v = acc[fm][fn][j] + bs[fn];
                    if (RELU) v = fmaxf(v, 0.f);
                    if constexpr (sizeof(OutT) == 2) { unsigned short h = f2bf(v); C[row * N + col] = (OutT)h; pk[j] = h; }
                    else                             C[row * N + col] = v;
                }
                if constexpr (VTRANS) {
                    if (col >= 2 * NE) {    // V region: emit vt[bh][d][t] transposed
                        int d = col - 2 * NE;               // h*64 + dd
                        int b = (int)(t0 >> 10);            // whole 128-row band is one batch
                        long vofs = ((long)(b * NH) * NHS + d) * NT + (t0 & 1023);
                        *(ushort4v*)&vt[vofs] = pk;
                    }
                }
            }
        }
    }
}

// ---------------- batched square bf16 GEMM (weff = Wp@Wp per layer), T2 swizzle ----------------
__global__ __launch_bounds__(256) void gemm_weff_kernel(const unsigned short* __restrict__ A0,
                                                        const unsigned short* __restrict__ B0,
                                                        unsigned short* __restrict__ C0,
                                                        int gridM, int N, int K) {
    __shared__ unsigned short As[2][128 * 32];
    __shared__ unsigned short Bs[2][128 * 32];
    long zofs = (long)blockIdx.z * N * K;
    const unsigned short* A = A0 + zofs;
    const unsigned short* BT = B0 + zofs;
    unsigned short* C = C0 + zofs;
    int tid = threadIdx.x;
    int lane = tid & 63, w = tid >> 6;
    int wr = w >> 1, wc = w & 1;
    int l4 = lane >> 4, l15 = lane & 15;
    int bm = blockIdx.x % gridM, bn = blockIdx.x / gridM;
    int m0 = bm * 128, n0 = bn * 128;

    f32x4 acc[4][4] = {};
    int srow = lane >> 2;
    int scol = ((lane & 3) ^ ((lane >> 3) & 3)) * 8;
    int rsw  = (l4 ^ ((l15 >> 1) & 3)) * 8;

    #pragma unroll
    for (int it = 0; it < 2; ++it) {
        int rr = w * 32 + it * 16;
        gload_lds16(&A [(long)(m0 + rr + srow) * K + scol], &As[0][rr * 32]);
        gload_lds16(&BT[(long)(n0 + rr + srow) * K + scol], &Bs[0][rr * 32]);
    }
    int cur = 0;
    for (int k0 = 0; k0 < K; k0 += 32) {
        __syncthreads();
        if (k0 + 32 < K) {
            #pragma unroll
            for (int it = 0; it < 2; ++it) {
                int rr = w * 32 + it * 16;
                gload_lds16(&A [(long)(m0 + rr + srow) * K + k0 + 32 + scol], &As[cur ^ 1][rr * 32]);
                gload_lds16(&BT[(long)(n0 + rr + srow) * K + k0 + 32 + scol], &Bs[cur ^ 1][rr * 32]);
            }
        }
        short8 a[4], b[4];
        #pragma unroll
        for (int f = 0; f < 4; ++f) {
            a[f] = *(const short8*)&As[cur][(wr * 64 + f * 16 + l15) * 32 + rsw];
            b[f] = *(const short8*)&Bs[cur][(wc * 64 + f * 16 + l15) * 32 + rsw];
        }
        #pragma unroll
        for (int fm = 0; fm < 4; ++fm)
            #pragma unroll
            for (int fn = 0; fn < 4; ++fn)
                acc[fm][fn] = __builtin_amdgcn_mfma_f32_16x16x32_bf16(a[fm], b[fn], acc[fm][fn], 0, 0, 0);
        cur ^= 1;
    }
    #pragma unroll
    for (int fm = 0; fm < 4; ++fm)
        #pragma unroll
        for (int j = 0; j < 4; ++j) {
            long row = m0 + wr * 64 + fm * 16 + l4 * 4 + j;
            #pragma unroll
            for (int fn = 0; fn < 4; ++fn)
                C[row * N + n0 + wc * 64 + fn * 16 + l15] = f2bf(acc[fm][fn][j]);
        }
}

// ---------------- LM head: 256x128 tile, 8 waves, 3-slot ring BK=32, depth-2 vmcnt, nt stores ----------------
__global__ __launch_bounds__(512, 4) void gemm256x128_lse(const unsigned short* __restrict__ A,
                                                          const unsigned short* __restrict__ BT,
                                                          const float* __restrict__ bias,
                                                          float* __restrict__ C,
                                                          float* __restrict__ pm, float* __restrict__ ps,
                                                          int gridM, int N, int K) {
    __shared__ unsigned short Al[3][256 * 32];   // 48 KB
    __shared__ unsigned short Bl[3][128 * 32];   // 24 KB
    int tid = threadIdx.x;
    int lane = tid & 63, w = tid >> 6;
    int wm = w >> 1, wn = w & 1;
    int l4 = lane >> 4, l15 = lane & 15;

    int nwg = gridDim.x, orig = blockIdx.x;
    int q = nwg >> 3, r8 = nwg & 7;
    int xcd = orig & 7, ii = orig >> 3;
    int wg = (xcd < r8) ? (xcd * (q + 1) + ii) : (r8 * (q + 1) + (xcd - r8) * q + ii);
    int bm = wg % gridM, bn = wg / gridM;
    int m0 = bm * 256, n0 = bn * 128;

    int nkt = K >> 5;
    int srow = lane >> 2;
    int sslot = ((lane & 3) ^ ((lane >> 3) & 3)) * 8;

    auto STAGE = [&](int slot, int kt) {       // 3 gload_lds per wave
        #pragma unroll
        for (int p = 0; p < 2; ++p) {
            int r0 = p * 128 + w * 16;
            gload_lds16(&A[(long)(m0 + r0 + srow) * K + kt * 32 + sslot], &Al[slot][r0 * 32]);
        }
        int r0 = w * 16;
        gload_lds16(&BT[(long)(n0 + r0 + srow) * K + kt * 32 + sslot], &Bl[slot][r0 * 32]);
    };

    f32x4 acc[4][4] = {};
    int rsw = (l4 ^ ((l15 >> 1) & 3)) * 8;

    STAGE(0, 0);
    STAGE(1, 1);
    int s = 0;
    for (int t = 0; t < nkt; ++t) {
        if (t + 2 < nkt) STAGE((t + 2) % 3, t + 2);
        int ahead = nkt - 1 - t;
        if (ahead >= 2)      asm volatile("s_waitcnt vmcnt(6)" ::: "memory");
        else if (ahead == 1) asm volatile("s_waitcnt vmcnt(3)" ::: "memory");
        else                 asm volatile("s_waitcnt vmcnt(0)" ::: "memory");
        asm volatile("s_barrier" ::: "memory");                // slot s staged for all waves

        short8 af[4], bf[4];
        #pragma unroll
        for (int f = 0; f < 4; ++f) {
            af[f] = *(const short8*)&Al[s][(wm * 64 + f * 16 + l15) * 32 + rsw];
            bf[f] = *(const short8*)&Bl[s][(wn * 64 + f * 16 + l15) * 32 + rsw];
        }
        asm volatile("s_waitcnt lgkmcnt(0)" ::: "memory");
        asm volatile("s_barrier" ::: "memory");                // all reads of slot s done

        __builtin_amdgcn_s_setprio(1);
        #pragma unroll
        for (int fm = 0; fm < 4; ++fm)
            #pragma unroll
            for (int fn = 0; fn < 4; ++fn)
                acc[fm][fn] = __builtin_amdgcn_mfma_f32_16x16x32_bf16(af[fm], bf[fn], acc[fm][fn], 0, 0, 0);
        __builtin_amdgcn_s_setprio(0);
        s = (s + 1) % 3;
    }

    float bs[4];
    #pragma unroll
    for (int fn = 0; fn < 4; ++fn)
        bs[fn] = bias[n0 + wn * 64 + fn * 16 + l15];

    #pragma unroll
    for (int fm = 0; fm < 4; ++fm) {
        #pragma unroll
        for (int j = 0; j < 4; ++j) {
            long row = m0 + wm * 64 + fm * 16 + l4 * 4 + j;
            float v4[4];
            #pragma unroll
            for (int fn = 0; fn < 4; ++fn) {
                int col = n0 + wn * 64 + fn * 16 + l15;
                float v = acc[fm][fn][j] + bs[fn];
                __builtin_nontemporal_store(v, &C[row * N + col]);   // logits: write-once stream
                v4[fn] = v;
            }
            float mx = fmaxf(fmaxf(v4[0], v4[1]), fmaxf(v4[2], v4[3]));
            #pragma unroll
            for (int off = 1; off < 16; off <<= 1) mx = fmaxf(mx, __shfl_xor(mx, off));
            float sm = 0.f;
            #pragma unroll
            for (int fn = 0; fn < 4; ++fn) sm += __expf(v4[fn] - mx);
            #pragma unroll
            for (int off = 1; off < 16; off <<= 1) sm += __shfl_xor(sm, off);
            if (l15 == 0) {
                int pidx = bn * 2 + wn;
                pm[row * 512 + pidx] = mx;
                ps[row * 512 + pidx] = sm;
            }
        }
    }
}

// ---------------- flash attention, QBLK=128: wave-shared tile max, deferred lsum reduce ----------------
__global__ __launch_bounds__(512, 2) void fattn_kernel(const unsigned short* __restrict__ qkv,
                                                       const unsigned short* __restrict__ vt,
                                                       unsigned short* __restrict__ out) {
    __shared__ unsigned short Ks[2][64 * 64];     // 16 KB
    __shared__ unsigned short Vl[2][64 * 64];     // 16 KB
    __shared__ unsigned short Ps[8 * 16 * 64];    // 16 KB
    int qt = gridDim.x - 1 - blockIdx.x;          // heavy q-tiles first
    int bh = blockIdx.y;
    int b = bh / NH, h = bh % NH;
    int tid = threadIdx.x, lane = tid & 63, w = tid >> 6;   // w = 0..7
    int l4 = lane >> 4, l15 = lane & 15;
    long rowb = (long)b * NT;
    const float scale = 0.03608439182435161f;     // 768^-0.5 (reference scales by E)
    const unsigned short* vtp = vt + (long)bh * NHS * NT;

    const unsigned short* qptr = qkv + (rowb + qt * 128 + w * 16 + l15) * NQKV + h * NHS;
    short8 qa0 = *(const short8*)(qptr + l4 * 8);
    short8 qa1 = *(const short8*)(qptr + 32 + l4 * 8);

    f32x4 o[4] = {};
    float m = -INFINITY;                          // wave-shared running max
    float lsum[4] = {};                           // per-lane partials (reduced at end)

    int kr_r = tid >> 3, kr_c = (tid & 7) * 8;
    int vr_d = tid >> 3, vr_s = tid & 7;

    short8 kr, vr;
    auto LOADT = [&](int t) {
        int kbase = t * 64;
        kr = *(const short8*)(qkv + (rowb + kbase + kr_r) * NQKV + NE + h * NHS + kr_c);
        vr = *(const short8*)(vtp + (long)vr_d * NT + kbase + vr_s * 8);
    };

    int ntiles = 2 * qt + 2;
    LOADT(0);
    for (int t = 0; t < ntiles; ++t) {
        int cur = t & 1;
        *(short8*)&Ks[cur][kr_r * 64 + (kr_c ^ ((kr_r & 7) << 3))] = kr;
        *(short8*)&Vl[cur][vr_d * 64 + ((vr_s * 8) ^ ((vr_d & 7) << 3))] = vr;
        asm volatile("s_waitcnt lgkmcnt(0)" ::: "memory");
        if (t + 1 < ntiles) LOADT(t + 1);
        asm volatile("s_barrier" ::: "memory");

        f32x4 s[4];
        __builtin_amdgcn_s_setprio(1);
        #pragma unroll
        for (int fn = 0; fn < 4; ++fn) {
            int key = fn * 16 + l15;
            short8 kb0 = *(const short8*)&Ks[cur][key * 64 + ((l4 * 8) ^ ((key & 7) << 3))];
            short8 kb1 = *(const short8*)&Ks[cur][key * 64 + ((32 + l4 * 8) ^ ((key & 7) << 3))];
            f32x4 z = {};
            z = __builtin_amdgcn_mfma_f32_16x16x32_bf16(qa0, kb0, z, 0, 0, 0);
            s[fn] = __builtin_amdgcn_mfma_f32_16x16x32_bf16(qa1, kb1, z, 0, 0, 0);
        }
        __builtin_amdgcn_s_setprio(0);

        if (t >= 2 * qt) {
            #pragma unroll
            for (int fn = 0; fn < 4; ++fn) {
                int key = t * 64 + fn * 16 + l15;
                #pragma unroll
                for (int j = 0; j < 4; ++j) {
                    int qrow = qt * 128 + w * 16 + l4 * 4 + j;
                    s[fn][j] = (key <= qrow) ? s[fn][j] * scale : -1e30f;
                }
            }
        } else {
            #pragma unroll
            for (int fn = 0; fn < 4; ++fn)
                #pragma unroll
                for (int j = 0; j < 4; ++j)
                    s[fn][j] *= scale;
        }

        float tmax = -INFINITY;
        #pragma unroll
        for (int fn = 0; fn < 4; ++fn)
            #pragma unroll
            for (int j = 0; j < 4; ++j)
                tmax = fmaxf(tmax, s[fn][j]);
        #pragma unroll
        for (int off = 1; off < 64; off <<= 1) tmax = fmaxf(tmax, __shfl_xor(tmax, off));

        if (tmax > m) {
            float alpha = __expf(m - tmax);
            m = tmax;
            #pragma unroll
            for (int j = 0; j < 4; ++j) lsum[j] *= alpha;
            #pragma unroll
            for (int fn = 0; fn < 4; ++fn)
                #pragma unroll
                for (int j = 0; j < 4; ++j) o[fn][j] *= alpha;
        }

        #pragma unroll
        for (int j = 0; j < 4; ++j) {
            float psum = 0.f;
            #pragma unroll
            for (int fn = 0; fn < 4; ++fn) {
                float p = __expf(s[fn][j] - m);
                psum += p;
                int rr = l4 * 4 + j, c = fn * 16 + l15;
                Ps[w * 1024 + rr * 64 + (c ^ ((rr & 7) << 3))] = f2bf(p);
            }
            lsum[j] += psum;
        }

        short8 pa0 = *(const short8*)&Ps[w * 1024 + l15 * 64 + ((l4 * 8) ^ ((l15 & 7) << 3))];
        short8 pa1 = *(const short8*)&Ps[w * 1024 + l15 * 64 + ((32 + l4 * 8) ^ ((l15 & 7) << 3))];
        __builtin_amdgcn_s_setprio(1);
        #pragma unroll
        for (int fn = 0; fn < 4; ++fn) {
            int d = fn * 16 + l15;
            short8 vb0 = *(const short8*)&Vl[cur][d * 64 + ((l4 * 8) ^ ((d & 7) << 3))];
            short8 vb1 = *(const short8*)&Vl[cur][d * 64 + ((32 + l4 * 8) ^ ((d & 7) << 3))];
            o[fn] = __builtin_amdgcn_mfma_f32_16x16x32_bf16(pa0, vb0, o[fn], 0, 0, 0);
            o[fn] = __builtin_amdgcn_mfma_f32_16x16x32_bf16(pa1, vb1, o[fn], 0, 0, 0);
        }
        __builtin_amdgcn_s_setprio(0);
    }

    #pragma unroll
    for (int j = 0; j < 4; ++j)
        #pragma unroll
        for (int off = 1; off < 16; off <<= 1)
            lsum[j] += __shfl_xor(lsum[j], off);

    #pragma unroll
    for (int j = 0; j < 4; ++j) {
        long row = rowb + qt * 128 + w * 16 + l4 * 4 + j;
        float inv = 1.0f / lsum[j];
        #pragma unroll
        for (int fn = 0; fn < 4; ++fn)
            out[row * NE + h * NHS + fn * 16 + l15] = f2bf(o[fn][j] * inv);
    }
}

// ---------------- NLL from LM-head partials ----------------
__global__ __launch_bounds__(256) void nll_combine_kernel(const float* __restrict__ logits,
                                                          const float* __restrict__ pm,
                                                          const float* __restrict__ ps,
                                                          const int* __restrict__ targets,
                                                          float* __restrict__ nll) {
    __shared__ float rm[256], rs[256];
    int row = blockIdx.x, tid = threadIdx.x;
    float m = -1e30f, s = 0.f;
    for (int i = tid; i < 500; i += 256) {
        float m2 = pm[(long)row * 512 + i], s2 = ps[(long)row * 512 + i];
        float mm = fmaxf(m, m2);
        s = s * __expf(m - mm) + s2 * __expf(m2 - mm);
        m = mm;
    }
    rm[tid] = m; rs[tid] = s; __syncthreads();
    for (int o = 128; o > 0; o >>= 1) {
        if (tid < o) {
            float m2 = rm[tid + o], s2 = rs[tid + o];
            float mm = fmaxf(rm[tid], m2);
            rs[tid] = rs[tid] * __expf(rm[tid] - mm) + s2 * __expf(m2 - mm);
            rm[tid] = mm;
        }
        __syncthreads();
    }
    if (tid == 0) {
        int tgt = targets[row];
        nll[row] = -(logits[(long)row * NV + tgt] - rm[0] - logf(rs[0]));
    }
}

__global__ void loss_reduce_kernel(const float* __restrict__ nll, float* __restrict__ out) {
    __shared__ float red[256];
    int tid = threadIdx.x;
    float s = 0.f;
    for (int i = tid; i < NM; i += 256) s += nll[i];
    red[tid] = s; __syncthreads();
    for (int o = 128; o > 0; o >>= 1) { if (tid < o) red[tid] += red[tid + o]; __syncthreads(); }
    if (tid == 0) out[0] = red[0] / NM;
}

extern "C" void kernel_launch(void* const* d_in, const int* in_sizes, int n_in,
                              void* d_out, int out_size, void* d_ws, size_t ws_size,
                              hipStream_t stream) {
    const int*   idx     = (const int*)  d_in[0];
    const int*   targets = (const int*)  d_in[1];
    const float* tok     = (const float*)d_in[2];
    const float* pos     = (const float*)d_in[3];
    const float* ln1_g   = (const float*)d_in[4];
    const float* ln1_b   = (const float*)d_in[5];
    const float* wq      = (const float*)d_in[6];
    const float* wk      = (const float*)d_in[7];
    const float* wv      = (const float*)d_in[8];
    const float* wproj   = (const float*)d_in[9];
    const float* bproj   = (const float*)d_in[10];
    const float* ln2_g   = (const float*)d_in[11];
    const float* ln2_b   = (const float*)d_in[12];
    const float* w1      = (const float*)d_in[13];
    const float* b1      = (const float*)d_in[14];
    const float* w2      = (const float*)d_in[15];
    const float* b2      = (const float*)d_in[16];
    const float* lnf_g   = (const float*)d_in[17];
    const float* lnf_b   = (const float*)d_in[18];
    const float* lm_w    = (const float*)d_in[19];
    const float* lm_b    = (const float*)d_in[20];

    float* logits = (float*)d_out;
    float* loss   = logits + (long)NM * NV;

    char* p = (char*)d_ws;
    float*          x      = (float*)p;          p += (long)NM * NE * 4;
    unsigned short* hbuf   = (unsigned short*)p; p += (long)NM * NE * 2;
    unsigned short* qkv    = (unsigned short*)p; p += (long)NM * NQKV * 2;
    unsigned short* att    = (unsigned short*)p; p += (long)NM * NE * 2;
    unsigned short* hid    = (unsigned short*)p; p += (long)NM * NFF * 2;
    unsigned short* vt     = (unsigned short*)p; p += (long)NB * NH * NHS * NT * 2;
    float*          nll    = (float*)p;          p += (long)NM * 4;
    float*          pmb    = (float*)p;          p += (long)NM * 512 * 4;
    float*          psb    = (float*)p;          p += (long)NM * 512 * 4;
    unsigned short* parts  = (unsigned short*)p; p += (long)4 * NM * NE * 2;   // bf16 split-K partials
    unsigned short* wqkvT6 = (unsigned short*)p; p += (long)NL * NQKV * NE * 2;
    unsigned short* wprojT6= (unsigned short*)p; p += (long)NL * NE * NE * 2;
    unsigned short* wprojC6= (unsigned short*)p; p += (long)NL * NE * NE * 2;
    unsigned short* weffT6 = (unsigned short*)p; p += (long)NL * NE * NE * 2;
    float*          beff6  = (float*)p;          p += (long)NL * NE * 4;
    unsigned short* w1T6   = (unsigned short*)p; p += (long)NL * NFF * NE * 2;
    unsigned short* w2T6   = (unsigned short*)p; p += (long)NL * NE * NFF * 2;
    unsigned short* lmT    = (unsigned short*)p; p += (long)NV * NE * 2;

    dim3 blk(256);

    // ---- batched weight prep ----
    transpose4b_kernel<<<dim3(NE / 32, NE / 32, 4 * NL), blk, 0, stream>>>(
        wq, wk, wv, wproj, wqkvT6, wprojT6, wprojC6);
    transpose_ffn_kernel<<<dim3(NFF / 32, NE / 32, 2 * NL), blk, 0, stream>>>(w1, w2, w1T6, w2T6);
    gemm_weff_kernel<<<dim3(36, 1, NL), blk, 0, stream>>>(wprojT6, wprojC6, weffT6, 6, NE, NE);
    beff_b_kernel<<<dim3(NE, NL), blk, 0, stream>>>(bproj, wprojT6, beff6);
    transpose_cast_kernel<<<dim3(NV / 32, NE / 32), blk, 0, stream>>>(lm_w, lmT, NE, NV);

    // ---- embedding + LN1(0) ----
    embed_ln_kernel<<<NM, blk, 0, stream>>>(idx, tok, pos, ln1_g, ln1_b, x, hbuf);

    for (int l = 0; l < NL; ++l) {
        // QKV: direct bf16 output + fused V-transpose epilogue
        gemm_mfma<unsigned short, false, false, 1, true><<<dim3((NM/128)*(NQKV/128)), blk, 0, stream>>>(
            hbuf, wqkvT6 + (long)l * NQKV * NE, nullptr, qkv, vt, NM / 128, NQKV, NE);
        fattn_kernel<<<dim3(NT / 128, NB * NH), dim3(512), 0, stream>>>(qkv, vt, att);
        gemm_mfma<unsigned short, false, false, 2, false><<<dim3((NM/128)*(NE/128), 2), blk, 0, stream>>>(
            att, weffT6 + (long)l * NE * NE, nullptr, parts, nullptr, NM / 128, NE, NE);
        combine_ln_kernel<2><<<NM, blk, 0, stream>>>(
            parts, beff6 + (long)l * NE, x, ln2_g + (long)l * NE, ln2_b + (long)l * NE, hbuf);
        gemm_mfma<unsigned short, true, true, 1, false><<<dim3((NM/128)*(NFF/128)), blk, 0, stream>>>(
            hbuf, w1T6 + (long)l * NFF * NE, b1 + (long)l * NFF, hid, nullptr, NM / 128, NFF, NE);
        gemm_mfma<unsigned short, false, false, 3, false><<<dim3((NM/128)*(NE/128), 3), blk, 0, stream>>>(
            hid, w2T6 + (long)l * NE * NFF, nullptr, parts, nullptr, NM / 128, NE, NFF);
        const float* ng = (l < NL - 1) ? (ln1_g + (long)(l + 1) * NE) : lnf_g;
        const float* nb = (l < NL - 1) ? (ln1_b + (long)(l + 1) * NE) : lnf_b;
        combine_ln_kernel<3><<<NM, blk, 0, stream>>>(parts, b2 + (long)l * NE, x, ng, nb, hbuf);
    }

    // ---- LM head + fused LSE ----
    gemm256x128_lse<<<dim3((NM/256)*(NV/128)), dim3(512), 0, stream>>>(
        hbuf, lmT, lm_b, logits, pmb, psb, NM / 256, NV, NE);
    nll_combine_kernel<<<NM, blk, 0, stream>>>(logits, pmb, psb, targets, nll);
    loss_reduce_kernel<<<1, blk, 0, stream>>>(nll, loss);
}

// Round 16
// 1004.293 us; speedup vs baseline: 1.0255x; 1.0255x over previous
//
#include <hip/hip_runtime.h>
#include <math.h>

#define NL 6
#define NH 12
#define NE 768
#define NHS 64
#define NT 1024
#define NB 2
#define NV 32000
#define NM (NB * NT)   // 2048
#define NQKV (3 * NE)  // 2304
#define NFF (4 * NE)   // 3072
#define LN_EPS 1e-5f

typedef __attribute__((ext_vector_type(8))) short short8;
typedef __attribute__((ext_vector_type(4))) float f32x4;
typedef __attribute__((ext_vector_type(4))) unsigned short ushort4v;
typedef __attribute__((address_space(1))) const unsigned int as1_cuint;
typedef __attribute__((address_space(3))) unsigned int as3_uint;

__device__ __forceinline__ unsigned short f2bf(float f) {
    unsigned int u = __builtin_bit_cast(unsigned int, f);
    u += 0x7fffu + ((u >> 16) & 1u);   // RNE
    return (unsigned short)(u >> 16);
}
__device__ __forceinline__ float bf2f(unsigned short u) {
    unsigned int v = ((unsigned int)u) << 16;
    return __builtin_bit_cast(float, v);
}
__device__ __forceinline__ void gload_lds16(const void* g, void* l) {
    __builtin_amdgcn_global_load_lds((as1_cuint*)g, (as3_uint*)l, 16, 0, 0);
}

// ---------------- embedding + LN1(layer0) fused: one block per row ----------------
__global__ __launch_bounds__(256) void embed_ln_kernel(const int* __restrict__ idx,
                                                       const float* __restrict__ tok,
                                                       const float* __restrict__ pos,
                                                       const float* __restrict__ g,
                                                       const float* __restrict__ b,
                                                       float* __restrict__ x,
                                                       unsigned short* __restrict__ hbuf) {
    __shared__ float red[256];
    int row = blockIdx.x, tid = threadIdx.x;
    int t = row % NT;
    int id = idx[row];
    float v[3]; float s = 0.f;
    #pragma unroll
    for (int k = 0; k < 3; ++k) {
        int c = tid + k * 256;
        v[k] = tok[(long)id * NE + c] + pos[(long)t * NE + c];
        x[(long)row * NE + c] = v[k];
        s += v[k];
    }
    red[tid] = s; __syncthreads();
    for (int o = 128; o > 0; o >>= 1) { if (tid < o) red[tid] += red[tid + o]; __syncthreads(); }
    float mu = red[0] / NE;
    __syncthreads();
    float vr = 0.f;
    #pragma unroll
    for (int k = 0; k < 3; ++k) { float d = v[k] - mu; vr += d * d; }
    red[tid] = vr; __syncthreads();
    for (int o = 128; o > 0; o >>= 1) { if (tid < o) red[tid] += red[tid + o]; __syncthreads(); }
    float rstd = rsqrtf(red[0] / NE + LN_EPS);
    #pragma unroll
    for (int k = 0; k < 3; ++k) {
        int c = tid + k * 256;
        hbuf[(long)row * NE + c] = f2bf((v[k] - mu) * rstd * g[c] + b[c]);
    }
}

// ---------------- fused split-K combine (bf16 parts) + residual + LayerNorm ----------------
template<int S>
__global__ __launch_bounds__(256) void combine_ln_kernel(const unsigned short* __restrict__ parts,
                                                         const float* __restrict__ bias,
                                                         float* __restrict__ x,
                                                         const float* __restrict__ g,
                                                         const float* __restrict__ b,
                                                         unsigned short* __restrict__ hbuf) {
    __shared__ float red[256];
    int row = blockIdx.x, tid = threadIdx.x;
    float v[3]; float s = 0.f;
    #pragma unroll
    for (int k = 0; k < 3; ++k) {
        int c = tid + k * 256;
        long i = (long)row * NE + c;
        float a = bf2f(parts[i]);
        #pragma unroll
        for (int si = 1; si < S; ++si) a += bf2f(parts[(long)si * NM * NE + i]);
        a += bias[c] + x[i];
        x[i] = a;
        v[k] = a; s += a;
    }
    red[tid] = s; __syncthreads();
    for (int o = 128; o > 0; o >>= 1) { if (tid < o) red[tid] += red[tid + o]; __syncthreads(); }
    float mu = red[0] / NE;
    __syncthreads();
    float vr = 0.f;
    #pragma unroll
    for (int k = 0; k < 3; ++k) { float d = v[k] - mu; vr += d * d; }
    red[tid] = vr; __syncthreads();
    for (int o = 128; o > 0; o >>= 1) { if (tid < o) red[tid] += red[tid + o]; __syncthreads(); }
    float rstd = rsqrtf(red[0] / NE + LN_EPS);
    #pragma unroll
    for (int k = 0; k < 3; ++k) {
        int c = tid + k * 256;
        hbuf[(long)row * NE + c] = f2bf((v[k] - mu) * rstd * g[c] + b[c]);
    }
}

// ---------------- batched transpose of the four 768x768 weights (+ straight cast of wproj) ----------------
__global__ __launch_bounds__(256) void transpose4b_kernel(const float* __restrict__ wq,
                                                          const float* __restrict__ wk,
                                                          const float* __restrict__ wv,
                                                          const float* __restrict__ wp,
                                                          unsigned short* __restrict__ wqkvT,
                                                          unsigned short* __restrict__ wprojT,
                                                          unsigned short* __restrict__ wprojC) {
    __shared__ float t[32][33];
    int z = blockIdx.z, l = z >> 2, which = z & 3;
    const float* W = ((which == 0) ? wq : (which == 1) ? wk : (which == 2) ? wv : wp) + (long)l * NE * NE;
    unsigned short* WT = (which < 3) ? (wqkvT + (long)l * NQKV * NE + (long)which * NE * NE)
                                     : (wprojT + (long)l * NE * NE);
    int k0 = blockIdx.y * 32, n0 = blockIdx.x * 32;
    int c = threadIdx.x & 31, r = threadIdx.x >> 5;
    #pragma unroll
    for (int p = 0; p < 4; ++p)
        t[r + p * 8][c] = W[(long)(k0 + r + p * 8) * NE + n0 + c];
    __syncthreads();
    #pragma unroll
    for (int p = 0; p < 4; ++p)
        WT[(long)(n0 + r + p * 8) * NE + k0 + c] = f2bf(t[c][r + p * 8]);
    if (which == 3) {   // also emit non-transposed bf16 copy (B-operand for weff GEMM)
        unsigned short* WC = wprojC + (long)l * NE * NE;
        #pragma unroll
        for (int p = 0; p < 4; ++p)
            WC[(long)(k0 + r + p * 8) * NE + n0 + c] = f2bf(t[r + p * 8][c]);
    }
}

// ---------------- merged w1/w2 transpose: z<NL -> w1 [NE][NFF], else w2 [NFF][NE] ----------------
__global__ __launch_bounds__(256) void transpose_ffn_kernel(const float* __restrict__ w1,
                                                            const float* __restrict__ w2,
                                                            unsigned short* __restrict__ w1T,
                                                            unsigned short* __restrict__ w2T) {
    __shared__ float t[32][33];
    int z = blockIdx.z;
    bool isW1 = z < NL;
    int l = isW1 ? z : z - NL;
    const float* W = (isW1 ? w1 : w2) + (long)l * NE * NFF;
    unsigned short* WT = (isW1 ? w1T : w2T) + (long)l * NE * NFF;
    int K = isW1 ? NE : NFF, N = isW1 ? NFF : NE;
    int k0 = (isW1 ? blockIdx.y : blockIdx.x) * 32;
    int n0 = (isW1 ? blockIdx.x : blockIdx.y) * 32;
    int c = threadIdx.x & 31, r = threadIdx.x >> 5;
    #pragma unroll
    for (int p = 0; p < 4; ++p)
        t[r + p * 8][c] = W[(long)(k0 + r + p * 8) * N + n0 + c];
    __syncthreads();
    #pragma unroll
    for (int p = 0; p < 4; ++p)
        WT[(long)(n0 + r + p * 8) * K + k0 + c] = f2bf(t[c][r + p * 8]);
}

// ---------------- tiled transpose + cast (lm head) ----------------
__global__ __launch_bounds__(256) void transpose_cast_kernel(const float* __restrict__ W,
                                                             unsigned short* __restrict__ WT,
                                                             int K, int N) {
    __shared__ float t[32][33];
    int k0 = blockIdx.y * 32, n0 = blockIdx.x * 32;
    int c = threadIdx.x & 31, r = threadIdx.x >> 5;
    #pragma unroll
    for (int p = 0; p < 4; ++p)
        t[r + p * 8][c] = W[(long)(k0 + r + p * 8) * N + n0 + c];
    __syncthreads();
    #pragma unroll
    for (int p = 0; p < 4; ++p)
        WT[(long)(n0 + r + p * 8) * K + k0 + c] = f2bf(t[c][r + p * 8]);
}

// ---------------- batched beff ----------------
__global__ __launch_bounds__(256) void beff_b_kernel(const float* __restrict__ bproj,
                                                     const unsigned short* __restrict__ wprojT,
                                                     float* __restrict__ beff) {
    __shared__ float red[256];
    int n = blockIdx.x, l = blockIdx.y, tid = threadIdx.x;
    const unsigned short* wp = wprojT + (long)l * NE * NE + (long)n * NE;
    const float* bp = bproj + (long)l * NE;
    float acc = 0.f;
    for (int j = tid; j < NE; j += 256) acc += bp[j] * bf2f(wp[j]);
    red[tid] = acc; __syncthreads();
    for (int o = 128; o > 0; o >>= 1) { if (tid < o) red[tid] += red[tid + o]; __syncthreads(); }
    if (tid == 0) beff[(long)l * NE + n] = red[0] + bp[n];
}

// ---------------- 128x128 bf16 MFMA GEMM: 3-slot ring, depth-2 counted vmcnt ----------------
// SPLITK>1: writes bf16 partials. VTRANS: V-columns (>=2*NE) also emitted transposed to vt.
template<typename OutT, bool BIAS, bool RELU, int SPLITK, bool VTRANS>
__global__ __launch_bounds__(256) void gemm_mfma(const unsigned short* __restrict__ A,
                                                 const unsigned short* __restrict__ BT,
                                                 const float* __restrict__ bias,
                                                 OutT* __restrict__ C,
                                                 unsigned short* __restrict__ vt,
                                                 int gridM, int N, int K) {
    __shared__ unsigned short As[3][128 * 32];
    __shared__ unsigned short Bs[3][128 * 32];
    int tid = threadIdx.x;
    int lane = tid & 63, w = tid >> 6;
    int wr = w >> 1, wc = w & 1;
    int l4 = lane >> 4, l15 = lane & 15;

    int nwg = gridDim.x, orig = blockIdx.x;
    int q = nwg >> 3, r8 = nwg & 7;
    int xcd = orig & 7, ii = orig >> 3;
    int wg = (xcd < r8) ? (xcd * (q + 1) + ii) : (r8 * (q + 1) + (xcd - r8) * q + ii);
    int bm = wg % gridM, bn = wg / gridM;
    int m0 = bm * 128, n0 = bn * 128;

    int kb = K / SPLITK;
    int koff = (SPLITK > 1) ? blockIdx.y * kb : 0;
    int nkt = kb >> 5;

    f32x4 acc[4][4] = {};

    int srow = lane >> 2;
    int scol = ((lane & 3) ^ ((lane >> 3) & 3)) * 8;   // inverse-swizzled source slot
    int rsw  = (l4 ^ ((l15 >> 1) & 3)) * 8;            // swizzled read slot

    auto STAGE = [&](int slot, int kt) {   // 4 gload_lds per wave
        #pragma unroll
        for (int it = 0; it < 2; ++it) {
            int rr = w * 32 + it * 16;
            gload_lds16(&A [(long)(m0 + rr + srow) * K + koff + kt * 32 + scol], &As[slot][rr * 32]);
            gload_lds16(&BT[(long)(n0 + rr + srow) * K + koff + kt * 32 + scol], &Bs[slot][rr * 32]);
        }
    };

    STAGE(0, 0);
    if (nkt > 1) STAGE(1, 1);

    int s = 0;
    for (int t = 0; t < nkt; ++t) {
        if (t + 2 < nkt) STAGE((t + 2) % 3, t + 2);
        int ahead = nkt - 1 - t;
        if (ahead >= 2)      asm volatile("s_waitcnt vmcnt(8)" ::: "memory");
        else if (ahead == 1) asm volatile("s_waitcnt vmcnt(4)" ::: "memory");
        else                 asm volatile("s_waitcnt vmcnt(0)" ::: "memory");
        asm volatile("s_barrier" ::: "memory");        // slot s fully staged for all waves

        short8 a[4], b[4];
        #pragma unroll
        for (int f = 0; f < 4; ++f) {
            a[f] = *(const short8*)&As[s][(wr * 64 + f * 16 + l15) * 32 + rsw];
            b[f] = *(const short8*)&Bs[s][(wc * 64 + f * 16 + l15) * 32 + rsw];
        }
        asm volatile("s_waitcnt lgkmcnt(0)" ::: "memory");
        asm volatile("s_barrier" ::: "memory");        // all reads of slot s done -> restageable

        __builtin_amdgcn_s_setprio(1);
        #pragma unroll
        for (int fm = 0; fm < 4; ++fm)
            #pragma unroll
            for (int fn = 0; fn < 4; ++fn)
                acc[fm][fn] = __builtin_amdgcn_mfma_f32_16x16x32_bf16(a[fm], b[fn], acc[fm][fn], 0, 0, 0);
        __builtin_amdgcn_s_setprio(0);
        s = (s + 1) % 3;
    }

    if constexpr (SPLITK > 1) {
        unsigned short* Cp = (unsigned short*)C + (long)blockIdx.y * gridM * 128 * N;
        #pragma unroll
        for (int fm = 0; fm < 4; ++fm)
            #pragma unroll
            for (int j = 0; j < 4; ++j) {
                long row = m0 + wr * 64 + fm * 16 + l4 * 4 + j;
                #pragma unroll
                for (int fn = 0; fn < 4; ++fn)
                    Cp[row * N + n0 + wc * 64 + fn * 16 + l15] = f2bf(acc[fm][fn][j]);
            }
    } else {
        float bs[4];
        #pragma unroll
        for (int fn = 0; fn < 4; ++fn)
            bs[fn] = BIAS ? bias[n0 + wc * 64 + fn * 16 + l15] : 0.f;

        #pragma unroll
        for (int fm = 0; fm < 4; ++fm) {
            #pragma unroll
            for (int fn = 0; fn < 4; ++fn) {
                int col = n0 + wc * 64 + fn * 16 + l15;
                long t0 = m0 + wr * 64 + fm * 16 + l4 * 4;
                ushort4v pk;
                #pragma unroll
                for (int j = 0; j < 4; ++j) {
                    long row = t0 + j;
                    float v = acc[fm][fn][j] + bs[fn];
                    if (RELU) v = fmaxf(v, 0.f);
                    if constexpr (sizeof(OutT) == 2) { unsigned short h = f2bf(v); C[row * N + col] = (OutT)h; pk[j] = h; }
                    else                             C[row * N + col] = v;
                }
                if constexpr (VTRANS) {
                    if (col >= 2 * NE) {    // V region: emit vt[bh][d][t] transposed
                        int d = col - 2 * NE;               // h*64 + dd
                        int b = (int)(t0 >> 10);            // whole 128-row band is one batch
                        long vofs = ((long)(b * NH) * NHS + d) * NT + (t0 & 1023);
                        *(ushort4v*)&vt[vofs] = pk;
                    }
                }
            }
        }
    }
}

// ---------------- batched square bf16 GEMM (weff = Wp@Wp per layer), T2 swizzle ----------------
__global__ __launch_bounds__(256) void gemm_weff_kernel(const unsigned short* __restrict__ A0,
                                                        const unsigned short* __restrict__ B0,
                                                        unsigned short* __restrict__ C0,
                                                        int gridM, int N, int K) {
    __shared__ unsigned short As[2][128 * 32];
    __shared__ unsigned short Bs[2][128 * 32];
    long zofs = (long)blockIdx.z * N * K;
    const unsigned short* A = A0 + zofs;
    const unsigned short* BT = B0 + zofs;
    unsigned short* C = C0 + zofs;
    int tid = threadIdx.x;
    int lane = tid & 63, w = tid >> 6;
    int wr = w >> 1, wc = w & 1;
    int l4 = lane >> 4, l15 = lane & 15;
    int bm = blockIdx.x % gridM, bn = blockIdx.x / gridM;
    int m0 = bm * 128, n0 = bn * 128;

    f32x4 acc[4][4] = {};
    int srow = lane >> 2;
    int scol = ((lane & 3) ^ ((lane >> 3) & 3)) * 8;
    int rsw  = (l4 ^ ((l15 >> 1) & 3)) * 8;

    #pragma unroll
    for (int it = 0; it < 2; ++it) {
        int rr = w * 32 + it * 16;
        gload_lds16(&A [(long)(m0 + rr + srow) * K + scol], &As[0][rr * 32]);
        gload_lds16(&BT[(long)(n0 + rr + srow) * K + scol], &Bs[0][rr * 32]);
    }
    int cur = 0;
    for (int k0 = 0; k0 < K; k0 += 32) {
        __syncthreads();
        if (k0 + 32 < K) {
            #pragma unroll
            for (int it = 0; it < 2; ++it) {
                int rr = w * 32 + it * 16;
                gload_lds16(&A [(long)(m0 + rr + srow) * K + k0 + 32 + scol], &As[cur ^ 1][rr * 32]);
                gload_lds16(&BT[(long)(n0 + rr + srow) * K + k0 + 32 + scol], &Bs[cur ^ 1][rr * 32]);
            }
        }
        short8 a[4], b[4];
        #pragma unroll
        for (int f = 0; f < 4; ++f) {
            a[f] = *(const short8*)&As[cur][(wr * 64 + f * 16 + l15) * 32 + rsw];
            b[f] = *(const short8*)&Bs[cur][(wc * 64 + f * 16 + l15) * 32 + rsw];
        }
        #pragma unroll
        for (int fm = 0; fm < 4; ++fm)
            #pragma unroll
            for (int fn = 0; fn < 4; ++fn)
                acc[fm][fn] = __builtin_amdgcn_mfma_f32_16x16x32_bf16(a[fm], b[fn], acc[fm][fn], 0, 0, 0);
        cur ^= 1;
    }
    #pragma unroll
    for (int fm = 0; fm < 4; ++fm)
        #pragma unroll
        for (int j = 0; j < 4; ++j) {
            long row = m0 + wr * 64 + fm * 16 + l4 * 4 + j;
            #pragma unroll
            for (int fn = 0; fn < 4; ++fn)
                C[row * N + n0 + wc * 64 + fn * 16 + l15] = f2bf(acc[fm][fn][j]);
        }
}

// ---------------- LM head: 256x128 tile, 8 waves, 3-slot ring BK=32, depth-2 vmcnt, nt stores ----------------
__global__ __launch_bounds__(512, 4) void gemm256x128_lse(const unsigned short* __restrict__ A,
                                                          const unsigned short* __restrict__ BT,
                                                          const float* __restrict__ bias,
                                                          float* __restrict__ C,
                                                          float* __restrict__ pm, float* __restrict__ ps,
                                                          int gridM, int N, int K) {
    __shared__ unsigned short Al[3][256 * 32];   // 48 KB
    __shared__ unsigned short Bl[3][128 * 32];   // 24 KB
    int tid = threadIdx.x;
    int lane = tid & 63, w = tid >> 6;
    int wm = w >> 1, wn = w & 1;
    int l4 = lane >> 4, l15 = lane & 15;

    int nwg = gridDim.x, orig = blockIdx.x;
    int q = nwg >> 3, r8 = nwg & 7;
    int xcd = orig & 7, ii = orig >> 3;
    int wg = (xcd < r8) ? (xcd * (q + 1) + ii) : (r8 * (q + 1) + (xcd - r8) * q + ii);
    int bm = wg % gridM, bn = wg / gridM;
    int m0 = bm * 256, n0 = bn * 128;

    int nkt = K >> 5;
    int srow = lane >> 2;
    int sslot = ((lane & 3) ^ ((lane >> 3) & 3)) * 8;

    auto STAGE = [&](int slot, int kt) {       // 3 gload_lds per wave
        #pragma unroll
        for (int p = 0; p < 2; ++p) {
            int r0 = p * 128 + w * 16;
            gload_lds16(&A[(long)(m0 + r0 + srow) * K + kt * 32 + sslot], &Al[slot][r0 * 32]);
        }
        int r0 = w * 16;
        gload_lds16(&BT[(long)(n0 + r0 + srow) * K + kt * 32 + sslot], &Bl[slot][r0 * 32]);
    };

    f32x4 acc[4][4] = {};
    int rsw = (l4 ^ ((l15 >> 1) & 3)) * 8;

    STAGE(0, 0);
    STAGE(1, 1);
    int s = 0;
    for (int t = 0; t < nkt; ++t) {
        if (t + 2 < nkt) STAGE((t + 2) % 3, t + 2);
        int ahead = nkt - 1 - t;
        if (ahead >= 2)      asm volatile("s_waitcnt vmcnt(6)" ::: "memory");
        else if (ahead == 1) asm volatile("s_waitcnt vmcnt(3)" ::: "memory");
        else                 asm volatile("s_waitcnt vmcnt(0)" ::: "memory");
        asm volatile("s_barrier" ::: "memory");                // slot s staged for all waves

        short8 af[4], bf[4];
        #pragma unroll
        for (int f = 0; f < 4; ++f) {
            af[f] = *(const short8*)&Al[s][(wm * 64 + f * 16 + l15) * 32 + rsw];
            bf[f] = *(const short8*)&Bl[s][(wn * 64 + f * 16 + l15) * 32 + rsw];
        }
        asm volatile("s_waitcnt lgkmcnt(0)" ::: "memory");
        asm volatile("s_barrier" ::: "memory");                // all reads of slot s done

        __builtin_amdgcn_s_setprio(1);
        #pragma unroll
        for (int fm = 0; fm < 4; ++fm)
            #pragma unroll
            for (int fn = 0; fn < 4; ++fn)
                acc[fm][fn] = __builtin_amdgcn_mfma_f32_16x16x32_bf16(af[fm], bf[fn], acc[fm][fn], 0, 0, 0);
        __builtin_amdgcn_s_setprio(0);
        s = (s + 1) % 3;
    }

    float bs[4];
    #pragma unroll
    for (int fn = 0; fn < 4; ++fn)
        bs[fn] = bias[n0 + wn * 64 + fn * 16 + l15];

    #pragma unroll
    for (int fm = 0; fm < 4; ++fm) {
        #pragma unroll
        for (int j = 0; j < 4; ++j) {
            long row = m0 + wm * 64 + fm * 16 + l4 * 4 + j;
            float v4[4];
            #pragma unroll
            for (int fn = 0; fn < 4; ++fn) {
                int col = n0 + wn * 64 + fn * 16 + l15;
                float v = acc[fm][fn][j] + bs[fn];
                __builtin_nontemporal_store(v, &C[row * N + col]);   // logits: write-once stream
                v4[fn] = v;
            }
            float mx = fmaxf(fmaxf(v4[0], v4[1]), fmaxf(v4[2], v4[3]));
            #pragma unroll
            for (int off = 1; off < 16; off <<= 1) mx = fmaxf(mx, __shfl_xor(mx, off));
            float sm = 0.f;
            #pragma unroll
            for (int fn = 0; fn < 4; ++fn) sm += __expf(v4[fn] - mx);
            #pragma unroll
            for (int off = 1; off < 16; off <<= 1) sm += __shfl_xor(sm, off);
            if (l15 == 0) {
                int pidx = bn * 2 + wn;
                pm[row * 512 + pidx] = mx;
                ps[row * 512 + pidx] = sm;
            }
        }
    }
}

// ---------------- flash attention, QBLK=128: wave-shared tile max, deferred lsum reduce ----------------
__global__ __launch_bounds__(512) void fattn_kernel(const unsigned short* __restrict__ qkv,
                                                    const unsigned short* __restrict__ vt,
                                                    unsigned short* __restrict__ out) {
    __shared__ unsigned short Ks[2][64 * 64];     // 16 KB
    __shared__ unsigned short Vl[2][64 * 64];     // 16 KB
    __shared__ unsigned short Ps[8 * 16 * 64];    // 16 KB
    int qt = gridDim.x - 1 - blockIdx.x;          // heavy q-tiles first
    int bh = blockIdx.y;
    int b = bh / NH, h = bh % NH;
    int tid = threadIdx.x, lane = tid & 63, w = tid >> 6;   // w = 0..7
    int l4 = lane >> 4, l15 = lane & 15;
    long rowb = (long)b * NT;
    const float scale = 0.03608439182435161f;     // 768^-0.5 (reference scales by E)
    const unsigned short* vtp = vt + (long)bh * NHS * NT;

    const unsigned short* qptr = qkv + (rowb + qt * 128 + w * 16 + l15) * NQKV + h * NHS;
    short8 qa0 = *(const short8*)(qptr + l4 * 8);
    short8 qa1 = *(const short8*)(qptr + 32 + l4 * 8);

    f32x4 o[4] = {};
    float m = -INFINITY;                          // wave-shared running max
    float lsum[4] = {};                           // per-lane partials (reduced at end)

    int kr_r = tid >> 3, kr_c = (tid & 7) * 8;
    int vr_d = tid >> 3, vr_s = tid & 7;

    short8 kr, vr;
    auto LOADT = [&](int t) {
        int kbase = t * 64;
        kr = *(const short8*)(qkv + (rowb + kbase + kr_r) * NQKV + NE + h * NHS + kr_c);
        vr = *(const short8*)(vtp + (long)vr_d * NT + kbase + vr_s * 8);
    };

    int ntiles = 2 * qt + 2;
    LOADT(0);
    for (int t = 0; t < ntiles; ++t) {
        int cur = t & 1;
        *(short8*)&Ks[cur][kr_r * 64 + (kr_c ^ ((kr_r & 7) << 3))] = kr;
        *(short8*)&Vl[cur][vr_d * 64 + ((vr_s * 8) ^ ((vr_d & 7) << 3))] = vr;
        asm volatile("s_waitcnt lgkmcnt(0)" ::: "memory");
        if (t + 1 < ntiles) LOADT(t + 1);
        asm volatile("s_barrier" ::: "memory");

        f32x4 s[4];
        __builtin_amdgcn_s_setprio(1);
        #pragma unroll
        for (int fn = 0; fn < 4; ++fn) {
            int key = fn * 16 + l15;
            short8 kb0 = *(const short8*)&Ks[cur][key * 64 + ((l4 * 8) ^ ((key & 7) << 3))];
            short8 kb1 = *(const short8*)&Ks[cur][key * 64 + ((32 + l4 * 8) ^ ((key & 7) << 3))];
            f32x4 z = {};
            z = __builtin_amdgcn_mfma_f32_16x16x32_bf16(qa0, kb0, z, 0, 0, 0);
            s[fn] = __builtin_amdgcn_mfma_f32_16x16x32_bf16(qa1, kb1, z, 0, 0, 0);
        }
        __builtin_amdgcn_s_setprio(0);

        if (t >= 2 * qt) {
            #pragma unroll
            for (int fn = 0; fn < 4; ++fn) {
                int key = t * 64 + fn * 16 + l15;
                #pragma unroll
                for (int j = 0; j < 4; ++j) {
                    int qrow = qt * 128 + w * 16 + l4 * 4 + j;
                    s[fn][j] = (key <= qrow) ? s[fn][j] * scale : -1e30f;
                }
            }
        } else {
            #pragma unroll
            for (int fn = 0; fn < 4; ++fn)
                #pragma unroll
                for (int j = 0; j < 4; ++j)
                    s[fn][j] *= scale;
        }

        float tmax = -INFINITY;
        #pragma unroll
        for (int fn = 0; fn < 4; ++fn)
            #pragma unroll
            for (int j = 0; j < 4; ++j)
                tmax = fmaxf(tmax, s[fn][j]);
        #pragma unroll
        for (int off = 1; off < 64; off <<= 1) tmax = fmaxf(tmax, __shfl_xor(tmax, off));

        if (tmax > m) {
            float alpha = __expf(m - tmax);
            m = tmax;
            #pragma unroll
            for (int j = 0; j < 4; ++j) lsum[j] *= alpha;
            #pragma unroll
            for (int fn = 0; fn < 4; ++fn)
                #pragma unroll
                for (int j = 0; j < 4; ++j) o[fn][j] *= alpha;
        }

        #pragma unroll
        for (int j = 0; j < 4; ++j) {
            float psum = 0.f;
            #pragma unroll
            for (int fn = 0; fn < 4; ++fn) {
                float p = __expf(s[fn][j] - m);
                psum += p;
                int rr = l4 * 4 + j, c = fn * 16 + l15;
                Ps[w * 1024 + rr * 64 + (c ^ ((rr & 7) << 3))] = f2bf(p);
            }
            lsum[j] += psum;
        }

        short8 pa0 = *(const short8*)&Ps[w * 1024 + l15 * 64 + ((l4 * 8) ^ ((l15 & 7) << 3))];
        short8 pa1 = *(const short8*)&Ps[w * 1024 + l15 * 64 + ((32 + l4 * 8) ^ ((l15 & 7) << 3))];
        __builtin_amdgcn_s_setprio(1);
        #pragma unroll
        for (int fn = 0; fn < 4; ++fn) {
            int d = fn * 16 + l15;
            short8 vb0 = *(const short8*)&Vl[cur][d * 64 + ((l4 * 8) ^ ((d & 7) << 3))];
            short8 vb1 = *(const short8*)&Vl[cur][d * 64 + ((32 + l4 * 8) ^ ((d & 7) << 3))];
            o[fn] = __builtin_amdgcn_mfma_f32_16x16x32_bf16(pa0, vb0, o[fn], 0, 0, 0);
            o[fn] = __builtin_amdgcn_mfma_f32_16x16x32_bf16(pa1, vb1, o[fn], 0, 0, 0);
        }
        __builtin_amdgcn_s_setprio(0);
    }

    #pragma unroll
    for (int j = 0; j < 4; ++j)
        #pragma unroll
        for (int off = 1; off < 16; off <<= 1)
            lsum[j] += __shfl_xor(lsum[j], off);

    #pragma unroll
    for (int j = 0; j < 4; ++j) {
        long row = rowb + qt * 128 + w * 16 + l4 * 4 + j;
        float inv = 1.0f / lsum[j];
        #pragma unroll
        for (int fn = 0; fn < 4; ++fn)
            out[row * NE + h * NHS + fn * 16 + l15] = f2bf(o[fn][j] * inv);
    }
}

// ---------------- NLL from LM-head partials ----------------
__global__ __launch_bounds__(256) void nll_combine_kernel(const float* __restrict__ logits,
                                                          const float* __restrict__ pm,
                                                          const float* __restrict__ ps,
                                                          const int* __restrict__ targets,
                                                          float* __restrict__ nll) {
    __shared__ float rm[256], rs[256];
    int row = blockIdx.x, tid = threadIdx.x;
    float m = -1e30f, s = 0.f;
    for (int i = tid; i < 500; i += 256) {
        float m2 = pm[(long)row * 512 + i], s2 = ps[(long)row * 512 + i];
        float mm = fmaxf(m, m2);
        s = s * __expf(m - mm) + s2 * __expf(m2 - mm);
        m = mm;
    }
    rm[tid] = m; rs[tid] = s; __syncthreads();
    for (int o = 128; o > 0; o >>= 1) {
        if (tid < o) {
            float m2 = rm[tid + o], s2 = rs[tid + o];
            float mm = fmaxf(rm[tid], m2);
            rs[tid] = rs[tid] * __expf(rm[tid] - mm) + s2 * __expf(m2 - mm);
            rm[tid] = mm;
        }
        __syncthreads();
    }
    if (tid == 0) {
        int tgt = targets[row];
        nll[row] = -(logits[(long)row * NV + tgt] - rm[0] - logf(rs[0]));
    }
}

__global__ void loss_reduce_kernel(const float* __restrict__ nll, float* __restrict__ out) {
    __shared__ float red[256];
    int tid = threadIdx.x;
    float s = 0.f;
    for (int i = tid; i < NM; i += 256) s += nll[i];
    red[tid] = s; __syncthreads();
    for (int o = 128; o > 0; o >>= 1) { if (tid < o) red[tid] += red[tid + o]; __syncthreads(); }
    if (tid == 0) out[0] = red[0] / NM;
}

extern "C" void kernel_launch(void* const* d_in, const int* in_sizes, int n_in,
                              void* d_out, int out_size, void* d_ws, size_t ws_size,
                              hipStream_t stream) {
    const int*   idx     = (const int*)  d_in[0];
    const int*   targets = (const int*)  d_in[1];
    const float* tok     = (const float*)d_in[2];
    const float* pos     = (const float*)d_in[3];
    const float* ln1_g   = (const float*)d_in[4];
    const float* ln1_b   = (const float*)d_in[5];
    const float* wq      = (const float*)d_in[6];
    const float* wk      = (const float*)d_in[7];
    const float* wv      = (const float*)d_in[8];
    const float* wproj   = (const float*)d_in[9];
    const float* bproj   = (const float*)d_in[10];
    const float* ln2_g   = (const float*)d_in[11];
    const float* ln2_b   = (const float*)d_in[12];
    const float* w1      = (const float*)d_in[13];
    const float* b1      = (const float*)d_in[14];
    const float* w2      = (const float*)d_in[15];
    const float* b2      = (const float*)d_in[16];
    const float* lnf_g   = (const float*)d_in[17];
    const float* lnf_b   = (const float*)d_in[18];
    const float* lm_w    = (const float*)d_in[19];
    const float* lm_b    = (const float*)d_in[20];

    float* logits = (float*)d_out;
    float* loss   = logits + (long)NM * NV;

    char* p = (char*)d_ws;
    float*          x      = (float*)p;          p += (long)NM * NE * 4;
    unsigned short* hbuf   = (unsigned short*)p; p += (long)NM * NE * 2;
    unsigned short* qkv    = (unsigned short*)p; p += (long)NM * NQKV * 2;
    unsigned short* att    = (unsigned short*)p; p += (long)NM * NE * 2;
    unsigned short* hid    = (unsigned short*)p; p += (long)NM * NFF * 2;
    unsigned short* vt     = (unsigned short*)p; p += (long)NB * NH * NHS * NT * 2;
    float*          nll    = (float*)p;          p += (long)NM * 4;
    float*          pmb    = (float*)p;          p += (long)NM * 512 * 4;
    float*          psb    = (float*)p;          p += (long)NM * 512 * 4;
    unsigned short* parts  = (unsigned short*)p; p += (long)4 * NM * NE * 2;   // bf16 split-K partials
    unsigned short* wqkvT6 = (unsigned short*)p; p += (long)NL * NQKV * NE * 2;
    unsigned short* wprojT6= (unsigned short*)p; p += (long)NL * NE * NE * 2;
    unsigned short* wprojC6= (unsigned short*)p; p += (long)NL * NE * NE * 2;
    unsigned short* weffT6 = (unsigned short*)p; p += (long)NL * NE * NE * 2;
    float*          beff6  = (float*)p;          p += (long)NL * NE * 4;
    unsigned short* w1T6   = (unsigned short*)p; p += (long)NL * NFF * NE * 2;
    unsigned short* w2T6   = (unsigned short*)p; p += (long)NL * NE * NFF * 2;
    unsigned short* lmT    = (unsigned short*)p; p += (long)NV * NE * 2;

    dim3 blk(256);

    // ---- batched weight prep ----
    transpose4b_kernel<<<dim3(NE / 32, NE / 32, 4 * NL), blk, 0, stream>>>(
        wq, wk, wv, wproj, wqkvT6, wprojT6, wprojC6);
    transpose_ffn_kernel<<<dim3(NFF / 32, NE / 32, 2 * NL), blk, 0, stream>>>(w1, w2, w1T6, w2T6);
    gemm_weff_kernel<<<dim3(36, 1, NL), blk, 0, stream>>>(wprojT6, wprojC6, weffT6, 6, NE, NE);
    beff_b_kernel<<<dim3(NE, NL), blk, 0, stream>>>(bproj, wprojT6, beff6);
    transpose_cast_kernel<<<dim3(NV / 32, NE / 32), blk, 0, stream>>>(lm_w, lmT, NE, NV);

    // ---- embedding + LN1(0) ----
    embed_ln_kernel<<<NM, blk, 0, stream>>>(idx, tok, pos, ln1_g, ln1_b, x, hbuf);

    for (int l = 0; l < NL; ++l) {
        // QKV: direct bf16 output + fused V-transpose epilogue
        gemm_mfma<unsigned short, false, false, 1, true><<<dim3((NM/128)*(NQKV/128)), blk, 0, stream>>>(
            hbuf, wqkvT6 + (long)l * NQKV * NE, nullptr, qkv, vt, NM / 128, NQKV, NE);
        fattn_kernel<<<dim3(NT / 128, NB * NH), dim3(512), 0, stream>>>(qkv, vt, att);
        gemm_mfma<unsigned short, false, false, 2, false><<<dim3((NM/128)*(NE/128), 2), blk, 0, stream>>>(
            att, weffT6 + (long)l * NE * NE, nullptr, parts, nullptr, NM / 128, NE, NE);
        combine_ln_kernel<2><<<NM, blk, 0, stream>>>(
            parts, beff6 + (long)l * NE, x, ln2_g + (long)l * NE, ln2_b + (long)l * NE, hbuf);
        gemm_mfma<unsigned short, true, true, 1, false><<<dim3((NM/128)*(NFF/128)), blk, 0, stream>>>(
            hbuf, w1T6 + (long)l * NFF * NE, b1 + (long)l * NFF, hid, nullptr, NM / 128, NFF, NE);
        gemm_mfma<unsigned short, false, false, 4, false><<<dim3((NM/128)*(NE/128), 4), blk, 0, stream>>>(
            hid, w2T6 + (long)l * NE * NFF, nullptr, parts, nullptr, NM / 128, NE, NFF);
        const float* ng = (l < NL - 1) ? (ln1_g + (long)(l + 1) * NE) : lnf_g;
        const float* nb = (l < NL - 1) ? (ln1_b + (long)(l + 1) * NE) : lnf_b;
        combine_ln_kernel<4><<<NM, blk, 0, stream>>>(parts, b2 + (long)l * NE, x, ng, nb, hbuf);
    }

    // ---- LM head + fused LSE ----
    gemm256x128_lse<<<dim3((NM/256)*(NV/128)), dim3(512), 0, stream>>>(
        hbuf, lmT, lm_b, logits, pmb, psb, NM / 256, NV, NE);
    nll_combine_kernel<<<NM, blk, 0, stream>>>(logits, pmb, psb, targets, nll);
    loss_reduce_kernel<<<1, blk, 0, stream>>>(nll, loss);
}

// Round 17
// 1003.375 us; speedup vs baseline: 1.0264x; 1.0009x over previous
//
#include <hip/hip_runtime.h>
#include <math.h>

#define NL 6
#define NH 12
#define NE 768
#define NHS 64
#define NT 1024
#define NB 2
#define NV 32000
#define NM (NB * NT)   // 2048
#define NQKV (3 * NE)  // 2304
#define NFF (4 * NE)   // 3072
#define LN_EPS 1e-5f

typedef __attribute__((ext_vector_type(8))) short short8;
typedef __attribute__((ext_vector_type(4))) float f32x4;
typedef __attribute__((ext_vector_type(4))) unsigned short ushort4v;
typedef __attribute__((address_space(1))) const unsigned int as1_cuint;
typedef __attribute__((address_space(3))) unsigned int as3_uint;

__device__ __forceinline__ unsigned short f2bf(float f) {
    unsigned int u = __builtin_bit_cast(unsigned int, f);
    u += 0x7fffu + ((u >> 16) & 1u);   // RNE
    return (unsigned short)(u >> 16);
}
__device__ __forceinline__ float bf2f(unsigned short u) {
    unsigned int v = ((unsigned int)u) << 16;
    return __builtin_bit_cast(float, v);
}
__device__ __forceinline__ void gload_lds16(const void* g, void* l) {
    __builtin_amdgcn_global_load_lds((as1_cuint*)g, (as3_uint*)l, 16, 0, 0);
}

// ---------------- embedding + LN1(layer0) fused: one block per row ----------------
__global__ __launch_bounds__(256) void embed_ln_kernel(const int* __restrict__ idx,
                                                       const float* __restrict__ tok,
                                                       const float* __restrict__ pos,
                                                       const float* __restrict__ g,
                                                       const float* __restrict__ b,
                                                       float* __restrict__ x,
                                                       unsigned short* __restrict__ hbuf) {
    __shared__ float red[256];
    int row = blockIdx.x, tid = threadIdx.x;
    int t = row % NT;
    int id = idx[row];
    float v[3]; float s = 0.f;
    #pragma unroll
    for (int k = 0; k < 3; ++k) {
        int c = tid + k * 256;
        v[k] = tok[(long)id * NE + c] + pos[(long)t * NE + c];
        x[(long)row * NE + c] = v[k];
        s += v[k];
    }
    red[tid] = s; __syncthreads();
    for (int o = 128; o > 0; o >>= 1) { if (tid < o) red[tid] += red[tid + o]; __syncthreads(); }
    float mu = red[0] / NE;
    __syncthreads();
    float vr = 0.f;
    #pragma unroll
    for (int k = 0; k < 3; ++k) { float d = v[k] - mu; vr += d * d; }
    red[tid] = vr; __syncthreads();
    for (int o = 128; o > 0; o >>= 1) { if (tid < o) red[tid] += red[tid + o]; __syncthreads(); }
    float rstd = rsqrtf(red[0] / NE + LN_EPS);
    #pragma unroll
    for (int k = 0; k < 3; ++k) {
        int c = tid + k * 256;
        hbuf[(long)row * NE + c] = f2bf((v[k] - mu) * rstd * g[c] + b[c]);
    }
}

// ---------------- fused split-K combine (bf16 parts) + residual + LayerNorm ----------------
template<int S>
__global__ __launch_bounds__(256) void combine_ln_kernel(const unsigned short* __restrict__ parts,
                                                         const float* __restrict__ bias,
                                                         float* __restrict__ x,
                                                         const float* __restrict__ g,
                                                         const float* __restrict__ b,
                                                         unsigned short* __restrict__ hbuf) {
    __shared__ float red[256];
    int row = blockIdx.x, tid = threadIdx.x;
    float v[3]; float s = 0.f;
    #pragma unroll
    for (int k = 0; k < 3; ++k) {
        int c = tid + k * 256;
        long i = (long)row * NE + c;
        float a = bf2f(parts[i]);
        #pragma unroll
        for (int si = 1; si < S; ++si) a += bf2f(parts[(long)si * NM * NE + i]);
        a += bias[c] + x[i];
        x[i] = a;
        v[k] = a; s += a;
    }
    red[tid] = s; __syncthreads();
    for (int o = 128; o > 0; o >>= 1) { if (tid < o) red[tid] += red[tid + o]; __syncthreads(); }
    float mu = red[0] / NE;
    __syncthreads();
    float vr = 0.f;
    #pragma unroll
    for (int k = 0; k < 3; ++k) { float d = v[k] - mu; vr += d * d; }
    red[tid] = vr; __syncthreads();
    for (int o = 128; o > 0; o >>= 1) { if (tid < o) red[tid] += red[tid + o]; __syncthreads(); }
    float rstd = rsqrtf(red[0] / NE + LN_EPS);
    #pragma unroll
    for (int k = 0; k < 3; ++k) {
        int c = tid + k * 256;
        hbuf[(long)row * NE + c] = f2bf((v[k] - mu) * rstd * g[c] + b[c]);
    }
}

// ---------------- batched transpose of the four 768x768 weights (+ straight cast of wproj) ----------------
__global__ __launch_bounds__(256) void transpose4b_kernel(const float* __restrict__ wq,
                                                          const float* __restrict__ wk,
                                                          const float* __restrict__ wv,
                                                          const float* __restrict__ wp,
                                                          unsigned short* __restrict__ wqkvT,
                                                          unsigned short* __restrict__ wprojT,
                                                          unsigned short* __restrict__ wprojC) {
    __shared__ float t[32][33];
    int z = blockIdx.z, l = z >> 2, which = z & 3;
    const float* W = ((which == 0) ? wq : (which == 1) ? wk : (which == 2) ? wv : wp) + (long)l * NE * NE;
    unsigned short* WT = (which < 3) ? (wqkvT + (long)l * NQKV * NE + (long)which * NE * NE)
                                     : (wprojT + (long)l * NE * NE);
    int k0 = blockIdx.y * 32, n0 = blockIdx.x * 32;
    int c = threadIdx.x & 31, r = threadIdx.x >> 5;
    #pragma unroll
    for (int p = 0; p < 4; ++p)
        t[r + p * 8][c] = W[(long)(k0 + r + p * 8) * NE + n0 + c];
    __syncthreads();
    #pragma unroll
    for (int p = 0; p < 4; ++p)
        WT[(long)(n0 + r + p * 8) * NE + k0 + c] = f2bf(t[c][r + p * 8]);
    if (which == 3) {   // also emit non-transposed bf16 copy (B-operand for weff GEMM)
        unsigned short* WC = wprojC + (long)l * NE * NE;
        #pragma unroll
        for (int p = 0; p < 4; ++p)
            WC[(long)(k0 + r + p * 8) * NE + n0 + c] = f2bf(t[r + p * 8][c]);
    }
}

// ---------------- merged w1/w2 transpose: z<NL -> w1 [NE][NFF], else w2 [NFF][NE] ----------------
__global__ __launch_bounds__(256) void transpose_ffn_kernel(const float* __restrict__ w1,
                                                            const float* __restrict__ w2,
                                                            unsigned short* __restrict__ w1T,
                                                            unsigned short* __restrict__ w2T) {
    __shared__ float t[32][33];
    int z = blockIdx.z;
    bool isW1 = z < NL;
    int l = isW1 ? z : z - NL;
    const float* W = (isW1 ? w1 : w2) + (long)l * NE * NFF;
    unsigned short* WT = (isW1 ? w1T : w2T) + (long)l * NE * NFF;
    int K = isW1 ? NE : NFF, N = isW1 ? NFF : NE;
    int k0 = (isW1 ? blockIdx.y : blockIdx.x) * 32;
    int n0 = (isW1 ? blockIdx.x : blockIdx.y) * 32;
    int c = threadIdx.x & 31, r = threadIdx.x >> 5;
    #pragma unroll
    for (int p = 0; p < 4; ++p)
        t[r + p * 8][c] = W[(long)(k0 + r + p * 8) * N + n0 + c];
    __syncthreads();
    #pragma unroll
    for (int p = 0; p < 4; ++p)
        WT[(long)(n0 + r + p * 8) * K + k0 + c] = f2bf(t[c][r + p * 8]);
}

// ---------------- tiled transpose + cast (lm head) ----------------
__global__ __launch_bounds__(256) void transpose_cast_kernel(const float* __restrict__ W,
                                                             unsigned short* __restrict__ WT,
                                                             int K, int N) {
    __shared__ float t[32][33];
    int k0 = blockIdx.y * 32, n0 = blockIdx.x * 32;
    int c = threadIdx.x & 31, r = threadIdx.x >> 5;
    #pragma unroll
    for (int p = 0; p < 4; ++p)
        t[r + p * 8][c] = W[(long)(k0 + r + p * 8) * N + n0 + c];
    __syncthreads();
    #pragma unroll
    for (int p = 0; p < 4; ++p)
        WT[(long)(n0 + r + p * 8) * K + k0 + c] = f2bf(t[c][r + p * 8]);
}

// ---------------- batched beff ----------------
__global__ __launch_bounds__(256) void beff_b_kernel(const float* __restrict__ bproj,
                                                     const unsigned short* __restrict__ wprojT,
                                                     float* __restrict__ beff) {
    __shared__ float red[256];
    int n = blockIdx.x, l = blockIdx.y, tid = threadIdx.x;
    const unsigned short* wp = wprojT + (long)l * NE * NE + (long)n * NE;
    const float* bp = bproj + (long)l * NE;
    float acc = 0.f;
    for (int j = tid; j < NE; j += 256) acc += bp[j] * bf2f(wp[j]);
    red[tid] = acc; __syncthreads();
    for (int o = 128; o > 0; o >>= 1) { if (tid < o) red[tid] += red[tid + o]; __syncthreads(); }
    if (tid == 0) beff[(long)l * NE + n] = red[0] + bp[n];
}

// ---------------- 128x128 bf16 MFMA GEMM: 3-slot ring, depth-2 counted vmcnt ----------------
// Second barrier AFTER the MFMA cluster: compiler interleaves ds_read with MFMA (fine lgkmcnt).
// SPLITK>1: writes bf16 partials. VTRANS: V-columns (>=2*NE) also emitted transposed to vt.
template<typename OutT, bool BIAS, bool RELU, int SPLITK, bool VTRANS>
__global__ __launch_bounds__(256) void gemm_mfma(const unsigned short* __restrict__ A,
                                                 const unsigned short* __restrict__ BT,
                                                 const float* __restrict__ bias,
                                                 OutT* __restrict__ C,
                                                 unsigned short* __restrict__ vt,
                                                 int gridM, int N, int K) {
    __shared__ unsigned short As[3][128 * 32];
    __shared__ unsigned short Bs[3][128 * 32];
    int tid = threadIdx.x;
    int lane = tid & 63, w = tid >> 6;
    int wr = w >> 1, wc = w & 1;
    int l4 = lane >> 4, l15 = lane & 15;

    int nwg = gridDim.x, orig = blockIdx.x;
    int q = nwg >> 3, r8 = nwg & 7;
    int xcd = orig & 7, ii = orig >> 3;
    int wg = (xcd < r8) ? (xcd * (q + 1) + ii) : (r8 * (q + 1) + (xcd - r8) * q + ii);
    int bm = wg % gridM, bn = wg / gridM;
    int m0 = bm * 128, n0 = bn * 128;

    int kb = K / SPLITK;
    int koff = (SPLITK > 1) ? blockIdx.y * kb : 0;
    int nkt = kb >> 5;

    f32x4 acc[4][4] = {};

    int srow = lane >> 2;
    int scol = ((lane & 3) ^ ((lane >> 3) & 3)) * 8;   // inverse-swizzled source slot
    int rsw  = (l4 ^ ((l15 >> 1) & 3)) * 8;            // swizzled read slot

    auto STAGE = [&](int slot, int kt) {   // 4 gload_lds per wave
        #pragma unroll
        for (int it = 0; it < 2; ++it) {
            int rr = w * 32 + it * 16;
            gload_lds16(&A [(long)(m0 + rr + srow) * K + koff + kt * 32 + scol], &As[slot][rr * 32]);
            gload_lds16(&BT[(long)(n0 + rr + srow) * K + koff + kt * 32 + scol], &Bs[slot][rr * 32]);
        }
    };

    STAGE(0, 0);
    if (nkt > 1) STAGE(1, 1);

    int s = 0;
    for (int t = 0; t < nkt; ++t) {
        if (t + 2 < nkt) STAGE((t + 2) % 3, t + 2);
        int ahead = nkt - 1 - t;
        if (ahead >= 2)      asm volatile("s_waitcnt vmcnt(8)" ::: "memory");
        else if (ahead == 1) asm volatile("s_waitcnt vmcnt(4)" ::: "memory");
        else                 asm volatile("s_waitcnt vmcnt(0)" ::: "memory");
        asm volatile("s_barrier" ::: "memory");        // slot s fully staged for all waves

        short8 a[4], b[4];
        #pragma unroll
        for (int f = 0; f < 4; ++f) {
            a[f] = *(const short8*)&As[s][(wr * 64 + f * 16 + l15) * 32 + rsw];
            b[f] = *(const short8*)&Bs[s][(wc * 64 + f * 16 + l15) * 32 + rsw];
        }
        // no lgkmcnt(0) pin: MFMAs depend on reads via data flow -> compiler emits
        // fine-grained counted waits and interleaves reads with MFMAs.
        __builtin_amdgcn_s_setprio(1);
        #pragma unroll
        for (int fm = 0; fm < 4; ++fm)
            #pragma unroll
            for (int fn = 0; fn < 4; ++fn)
                acc[fm][fn] = __builtin_amdgcn_mfma_f32_16x16x32_bf16(a[fm], b[fn], acc[fm][fn], 0, 0, 0);
        __builtin_amdgcn_s_setprio(0);
        asm volatile("s_barrier" ::: "memory");        // phase t done -> slot s restageable at t+1
        s = (s + 1) % 3;
    }

    if constexpr (SPLITK > 1) {
        unsigned short* Cp = (unsigned short*)C + (long)blockIdx.y * gridM * 128 * N;
        #pragma unroll
        for (int fm = 0; fm < 4; ++fm)
            #pragma unroll
            for (int j = 0; j < 4; ++j) {
                long row = m0 + wr * 64 + fm * 16 + l4 * 4 + j;
                #pragma unroll
                for (int fn = 0; fn < 4; ++fn)
                    Cp[row * N + n0 + wc * 64 + fn * 16 + l15] = f2bf(acc[fm][fn][j]);
            }
    } else {
        float bs[4];
        #pragma unroll
        for (int fn = 0; fn < 4; ++fn)
            bs[fn] = BIAS ? bias[n0 + wc * 64 + fn * 16 + l15] : 0.f;

        #pragma unroll
        for (int fm = 0; fm < 4; ++fm) {
            #pragma unroll
            for (int fn = 0; fn < 4; ++fn) {
                int col = n0 + wc * 64 + fn * 16 + l15;
                long t0 = m0 + wr * 64 + fm * 16 + l4 * 4;
                ushort4v pk;
                #pragma unroll
                for (int j = 0; j < 4; ++j) {
                    long row = t0 + j;
                    float v = acc[fm][fn][j] + bs[fn];
                    if (RELU) v = fmaxf(v, 0.f);
                    if constexpr (sizeof(OutT) == 2) { unsigned short h = f2bf(v); C[row * N + col] = (OutT)h; pk[j] = h; }
                    else                             C[row * N + col] = v;
                }
                if constexpr (VTRANS) {
                    if (col >= 2 * NE) {    // V region: emit vt[bh][d][t] transposed
                        int d = col - 2 * NE;               // h*64 + dd
                        int b = (int)(t0 >> 10);            // whole 128-row band is one batch
                        long vofs = ((long)(b * NH) * NHS + d) * NT + (t0 & 1023);
                        *(ushort4v*)&vt[vofs] = pk;
                    }
                }
            }
        }
    }
}

// ---------------- batched square bf16 GEMM (weff = Wp@Wp per layer), T2 swizzle ----------------
__global__ __launch_bounds__(256) void gemm_weff_kernel(const unsigned short* __restrict__ A0,
                                                        const unsigned short* __restrict__ B0,
                                                        unsigned short* __restrict__ C0,
                                                        int gridM, int N, int K) {
    __shared__ unsigned short As[2][128 * 32];
    __shared__ unsigned short Bs[2][128 * 32];
    long zofs = (long)blockIdx.z * N * K;
    const unsigned short* A = A0 + zofs;
    const unsigned short* BT = B0 + zofs;
    unsigned short* C = C0 + zofs;
    int tid = threadIdx.x;
    int lane = tid & 63, w = tid >> 6;
    int wr = w >> 1, wc = w & 1;
    int l4 = lane >> 4, l15 = lane & 15;
    int bm = blockIdx.x % gridM, bn = blockIdx.x / gridM;
    int m0 = bm * 128, n0 = bn * 128;

    f32x4 acc[4][4] = {};
    int srow = lane >> 2;
    int scol = ((lane & 3) ^ ((lane >> 3) & 3)) * 8;
    int rsw  = (l4 ^ ((l15 >> 1) & 3)) * 8;

    #pragma unroll
    for (int it = 0; it < 2; ++it) {
        int rr = w * 32 + it * 16;
        gload_lds16(&A [(long)(m0 + rr + srow) * K + scol], &As[0][rr * 32]);
        gload_lds16(&BT[(long)(n0 + rr + srow) * K + scol], &Bs[0][rr * 32]);
    }
    int cur = 0;
    for (int k0 = 0; k0 < K; k0 += 32) {
        __syncthreads();
        if (k0 + 32 < K) {
            #pragma unroll
            for (int it = 0; it < 2; ++it) {
                int rr = w * 32 + it * 16;
                gload_lds16(&A [(long)(m0 + rr + srow) * K + k0 + 32 + scol], &As[cur ^ 1][rr * 32]);
                gload_lds16(&BT[(long)(n0 + rr + srow) * K + k0 + 32 + scol], &Bs[cur ^ 1][rr * 32]);
            }
        }
        short8 a[4], b[4];
        #pragma unroll
        for (int f = 0; f < 4; ++f) {
            a[f] = *(const short8*)&As[cur][(wr * 64 + f * 16 + l15) * 32 + rsw];
            b[f] = *(const short8*)&Bs[cur][(wc * 64 + f * 16 + l15) * 32 + rsw];
        }
        #pragma unroll
        for (int fm = 0; fm < 4; ++fm)
            #pragma unroll
            for (int fn = 0; fn < 4; ++fn)
                acc[fm][fn] = __builtin_amdgcn_mfma_f32_16x16x32_bf16(a[fm], b[fn], acc[fm][fn], 0, 0, 0);
        cur ^= 1;
    }
    #pragma unroll
    for (int fm = 0; fm < 4; ++fm)
        #pragma unroll
        for (int j = 0; j < 4; ++j) {
            long row = m0 + wr * 64 + fm * 16 + l4 * 4 + j;
            #pragma unroll
            for (int fn = 0; fn < 4; ++fn)
                C[row * N + n0 + wc * 64 + fn * 16 + l15] = f2bf(acc[fm][fn][j]);
        }
}

// ---------------- LM head: 256x128 tile, 8 waves, 3-slot ring BK=32, depth-2 vmcnt, nt stores ----------------
// Second barrier AFTER the MFMA cluster (see gemm_mfma).
__global__ __launch_bounds__(512, 4) void gemm256x128_lse(const unsigned short* __restrict__ A,
                                                          const unsigned short* __restrict__ BT,
                                                          const float* __restrict__ bias,
                                                          float* __restrict__ C,
                                                          float* __restrict__ pm, float* __restrict__ ps,
                                                          int gridM, int N, int K) {
    __shared__ unsigned short Al[3][256 * 32];   // 48 KB
    __shared__ unsigned short Bl[3][128 * 32];   // 24 KB
    int tid = threadIdx.x;
    int lane = tid & 63, w = tid >> 6;
    int wm = w >> 1, wn = w & 1;
    int l4 = lane >> 4, l15 = lane & 15;

    int nwg = gridDim.x, orig = blockIdx.x;
    int q = nwg >> 3, r8 = nwg & 7;
    int xcd = orig & 7, ii = orig >> 3;
    int wg = (xcd < r8) ? (xcd * (q + 1) + ii) : (r8 * (q + 1) + (xcd - r8) * q + ii);
    int bm = wg % gridM, bn = wg / gridM;
    int m0 = bm * 256, n0 = bn * 128;

    int nkt = K >> 5;
    int srow = lane >> 2;
    int sslot = ((lane & 3) ^ ((lane >> 3) & 3)) * 8;

    auto STAGE = [&](int slot, int kt) {       // 3 gload_lds per wave
        #pragma unroll
        for (int p = 0; p < 2; ++p) {
            int r0 = p * 128 + w * 16;
            gload_lds16(&A[(long)(m0 + r0 + srow) * K + kt * 32 + sslot], &Al[slot][r0 * 32]);
        }
        int r0 = w * 16;
        gload_lds16(&BT[(long)(n0 + r0 + srow) * K + kt * 32 + sslot], &Bl[slot][r0 * 32]);
    };

    f32x4 acc[4][4] = {};
    int rsw = (l4 ^ ((l15 >> 1) & 3)) * 8;

    STAGE(0, 0);
    STAGE(1, 1);
    int s = 0;
    for (int t = 0; t < nkt; ++t) {
        if (t + 2 < nkt) STAGE((t + 2) % 3, t + 2);
        int ahead = nkt - 1 - t;
        if (ahead >= 2)      asm volatile("s_waitcnt vmcnt(6)" ::: "memory");
        else if (ahead == 1) asm volatile("s_waitcnt vmcnt(3)" ::: "memory");
        else                 asm volatile("s_waitcnt vmcnt(0)" ::: "memory");
        asm volatile("s_barrier" ::: "memory");                // slot s staged for all waves

        short8 af[4], bf[4];
        #pragma unroll
        for (int f = 0; f < 4; ++f) {
            af[f] = *(const short8*)&Al[s][(wm * 64 + f * 16 + l15) * 32 + rsw];
            bf[f] = *(const short8*)&Bl[s][(wn * 64 + f * 16 + l15) * 32 + rsw];
        }
        // no lgkmcnt(0) pin: compiler interleaves reads with MFMAs via counted waits
        __builtin_amdgcn_s_setprio(1);
        #pragma unroll
        for (int fm = 0; fm < 4; ++fm)
            #pragma unroll
            for (int fn = 0; fn < 4; ++fn)
                acc[fm][fn] = __builtin_amdgcn_mfma_f32_16x16x32_bf16(af[fm], bf[fn], acc[fm][fn], 0, 0, 0);
        __builtin_amdgcn_s_setprio(0);
        asm volatile("s_barrier" ::: "memory");                // phase t done -> slot restageable
        s = (s + 1) % 3;
    }

    float bs[4];
    #pragma unroll
    for (int fn = 0; fn < 4; ++fn)
        bs[fn] = bias[n0 + wn * 64 + fn * 16 + l15];

    #pragma unroll
    for (int fm = 0; fm < 4; ++fm) {
        #pragma unroll
        for (int j = 0; j < 4; ++j) {
            long row = m0 + wm * 64 + fm * 16 + l4 * 4 + j;
            float v4[4];
            #pragma unroll
            for (int fn = 0; fn < 4; ++fn) {
                int col = n0 + wn * 64 + fn * 16 + l15;
                float v = acc[fm][fn][j] + bs[fn];
                __builtin_nontemporal_store(v, &C[row * N + col]);   // logits: write-once stream
                v4[fn] = v;
            }
            float mx = fmaxf(fmaxf(v4[0], v4[1]), fmaxf(v4[2], v4[3]));
            #pragma unroll
            for (int off = 1; off < 16; off <<= 1) mx = fmaxf(mx, __shfl_xor(mx, off));
            float sm = 0.f;
            #pragma unroll
            for (int fn = 0; fn < 4; ++fn) sm += __expf(v4[fn] - mx);
            #pragma unroll
            for (int off = 1; off < 16; off <<= 1) sm += __shfl_xor(sm, off);
            if (l15 == 0) {
                int pidx = bn * 2 + wn;
                pm[row * 512 + pidx] = mx;
                ps[row * 512 + pidx] = sm;
            }
        }
    }
}

// ---------------- flash attention, QBLK=128: wave-shared tile max, deferred lsum reduce ----------------
__global__ __launch_bounds__(512) void fattn_kernel(const unsigned short* __restrict__ qkv,
                                                    const unsigned short* __restrict__ vt,
                                                    unsigned short* __restrict__ out) {
    __shared__ unsigned short Ks[2][64 * 64];     // 16 KB
    __shared__ unsigned short Vl[2][64 * 64];     // 16 KB
    __shared__ unsigned short Ps[8 * 16 * 64];    // 16 KB
    int qt = gridDim.x - 1 - blockIdx.x;          // heavy q-tiles first
    int bh = blockIdx.y;
    int b = bh / NH, h = bh % NH;
    int tid = threadIdx.x, lane = tid & 63, w = tid >> 6;   // w = 0..7
    int l4 = lane >> 4, l15 = lane & 15;
    long rowb = (long)b * NT;
    const float scale = 0.03608439182435161f;     // 768^-0.5 (reference scales by E)
    const unsigned short* vtp = vt + (long)bh * NHS * NT;

    const unsigned short* qptr = qkv + (rowb + qt * 128 + w * 16 + l15) * NQKV + h * NHS;
    short8 qa0 = *(const short8*)(qptr + l4 * 8);
    short8 qa1 = *(const short8*)(qptr + 32 + l4 * 8);

    f32x4 o[4] = {};
    float m = -INFINITY;                          // wave-shared running max
    float lsum[4] = {};                           // per-lane partials (reduced at end)

    int kr_r = tid >> 3, kr_c = (tid & 7) * 8;
    int vr_d = tid >> 3, vr_s = tid & 7;

    short8 kr, vr;
    auto LOADT = [&](int t) {
        int kbase = t * 64;
        kr = *(const short8*)(qkv + (rowb + kbase + kr_r) * NQKV + NE + h * NHS + kr_c);
        vr = *(const short8*)(vtp + (long)vr_d * NT + kbase + vr_s * 8);
    };

    int ntiles = 2 * qt + 2;
    LOADT(0);
    for (int t = 0; t < ntiles; ++t) {
        int cur = t & 1;
        *(short8*)&Ks[cur][kr_r * 64 + (kr_c ^ ((kr_r & 7) << 3))] = kr;
        *(short8*)&Vl[cur][vr_d * 64 + ((vr_s * 8) ^ ((vr_d & 7) << 3))] = vr;
        asm volatile("s_waitcnt lgkmcnt(0)" ::: "memory");
        if (t + 1 < ntiles) LOADT(t + 1);
        asm volatile("s_barrier" ::: "memory");

        f32x4 s[4];
        __builtin_amdgcn_s_setprio(1);
        #pragma unroll
        for (int fn = 0; fn < 4; ++fn) {
            int key = fn * 16 + l15;
            short8 kb0 = *(const short8*)&Ks[cur][key * 64 + ((l4 * 8) ^ ((key & 7) << 3))];
            short8 kb1 = *(const short8*)&Ks[cur][key * 64 + ((32 + l4 * 8) ^ ((key & 7) << 3))];
            f32x4 z = {};
            z = __builtin_amdgcn_mfma_f32_16x16x32_bf16(qa0, kb0, z, 0, 0, 0);
            s[fn] = __builtin_amdgcn_mfma_f32_16x16x32_bf16(qa1, kb1, z, 0, 0, 0);
        }
        __builtin_amdgcn_s_setprio(0);

        if (t >= 2 * qt) {
            #pragma unroll
            for (int fn = 0; fn < 4; ++fn) {
                int key = t * 64 + fn * 16 + l15;
                #pragma unroll
                for (int j = 0; j < 4; ++j) {
                    int qrow = qt * 128 + w * 16 + l4 * 4 + j;
                    s[fn][j] = (key <= qrow) ? s[fn][j] * scale : -1e30f;
                }
            }
        } else {
            #pragma unroll
            for (int fn = 0; fn < 4; ++fn)
                #pragma unroll
                for (int j = 0; j < 4; ++j)
                    s[fn][j] *= scale;
        }

        float tmax = -INFINITY;
        #pragma unroll
        for (int fn = 0; fn < 4; ++fn)
            #pragma unroll
            for (int j = 0; j < 4; ++j)
                tmax = fmaxf(tmax, s[fn][j]);
        #pragma unroll
        for (int off = 1; off < 64; off <<= 1) tmax = fmaxf(tmax, __shfl_xor(tmax, off));

        if (tmax > m) {
            float alpha = __expf(m - tmax);
            m = tmax;
            #pragma unroll
            for (int j = 0; j < 4; ++j) lsum[j] *= alpha;
            #pragma unroll
            for (int fn = 0; fn < 4; ++fn)
                #pragma unroll
                for (int j = 0; j < 4; ++j) o[fn][j] *= alpha;
        }

        #pragma unroll
        for (int j = 0; j < 4; ++j) {
            float psum = 0.f;
            #pragma unroll
            for (int fn = 0; fn < 4; ++fn) {
                float p = __expf(s[fn][j] - m);
                psum += p;
                int rr = l4 * 4 + j, c = fn * 16 + l15;
                Ps[w * 1024 + rr * 64 + (c ^ ((rr & 7) << 3))] = f2bf(p);
            }
            lsum[j] += psum;
        }

        short8 pa0 = *(const short8*)&Ps[w * 1024 + l15 * 64 + ((l4 * 8) ^ ((l15 & 7) << 3))];
        short8 pa1 = *(const short8*)&Ps[w * 1024 + l15 * 64 + ((32 + l4 * 8) ^ ((l15 & 7) << 3))];
        __builtin_amdgcn_s_setprio(1);
        #pragma unroll
        for (int fn = 0; fn < 4; ++fn) {
            int d = fn * 16 + l15;
            short8 vb0 = *(const short8*)&Vl[cur][d * 64 + ((l4 * 8) ^ ((d & 7) << 3))];
            short8 vb1 = *(const short8*)&Vl[cur][d * 64 + ((32 + l4 * 8) ^ ((d & 7) << 3))];
            o[fn] = __builtin_amdgcn_mfma_f32_16x16x32_bf16(pa0, vb0, o[fn], 0, 0, 0);
            o[fn] = __builtin_amdgcn_mfma_f32_16x16x32_bf16(pa1, vb1, o[fn], 0, 0, 0);
        }
        __builtin_amdgcn_s_setprio(0);
    }

    #pragma unroll
    for (int j = 0; j < 4; ++j)
        #pragma unroll
        for (int off = 1; off < 16; off <<= 1)
            lsum[j] += __shfl_xor(lsum[j], off);

    #pragma unroll
    for (int j = 0; j < 4; ++j) {
        long row = rowb + qt * 128 + w * 16 + l4 * 4 + j;
        float inv = 1.0f / lsum[j];
        #pragma unroll
        for (int fn = 0; fn < 4; ++fn)
            out[row * NE + h * NHS + fn * 16 + l15] = f2bf(o[fn][j] * inv);
    }
}

// ---------------- NLL from LM-head partials ----------------
__global__ __launch_bounds__(256) void nll_combine_kernel(const float* __restrict__ logits,
                                                          const float* __restrict__ pm,
                                                          const float* __restrict__ ps,
                                                          const int* __restrict__ targets,
                                                          float* __restrict__ nll) {
    __shared__ float rm[256], rs[256];
    int row = blockIdx.x, tid = threadIdx.x;
    float m = -1e30f, s = 0.f;
    for (int i = tid; i < 500; i += 256) {
        float m2 = pm[(long)row * 512 + i], s2 = ps[(long)row * 512 + i];
        float mm = fmaxf(m, m2);
        s = s * __expf(m - mm) + s2 * __expf(m2 - mm);
        m = mm;
    }
    rm[tid] = m; rs[tid] = s; __syncthreads();
    for (int o = 128; o > 0; o >>= 1) {
        if (tid < o) {
            float m2 = rm[tid + o], s2 = rs[tid + o];
            float mm = fmaxf(rm[tid], m2);
            rs[tid] = rs[tid] * __expf(rm[tid] - mm) + s2 * __expf(m2 - mm);
            rm[tid] = mm;
        }
        __syncthreads();
    }
    if (tid == 0) {
        int tgt = targets[row];
        nll[row] = -(logits[(long)row * NV + tgt] - rm[0] - logf(rs[0]));
    }
}

__global__ void loss_reduce_kernel(const float* __restrict__ nll, float* __restrict__ out) {
    __shared__ float red[256];
    int tid = threadIdx.x;
    float s = 0.f;
    for (int i = tid; i < NM; i += 256) s += nll[i];
    red[tid] = s; __syncthreads();
    for (int o = 128; o > 0; o >>= 1) { if (tid < o) red[tid] += red[tid + o]; __syncthreads(); }
    if (tid == 0) out[0] = red[0] / NM;
}

extern "C" void kernel_launch(void* const* d_in, const int* in_sizes, int n_in,
                              void* d_out, int out_size, void* d_ws, size_t ws_size,
                              hipStream_t stream) {
    const int*   idx     = (const int*)  d_in[0];
    const int*   targets = (const int*)  d_in[1];
    const float* tok     = (const float*)d_in[2];
    const float* pos     = (const float*)d_in[3];
    const float* ln1_g   = (const float*)d_in[4];
    const float* ln1_b   = (const float*)d_in[5];
    const float* wq      = (const float*)d_in[6];
    const float* wk      = (const float*)d_in[7];
    const float* wv      = (const float*)d_in[8];
    const float* wproj   = (const float*)d_in[9];
    const float* bproj   = (const float*)d_in[10];
    const float* ln2_g   = (const float*)d_in[11];
    const float* ln2_b   = (const float*)d_in[12];
    const float* w1      = (const float*)d_in[13];
    const float* b1      = (const float*)d_in[14];
    const float* w2      = (const float*)d_in[15];
    const float* b2      = (const float*)d_in[16];
    const float* lnf_g   = (const float*)d_in[17];
    const float* lnf_b   = (const float*)d_in[18];
    const float* lm_w    = (const float*)d_in[19];
    const float* lm_b    = (const float*)d_in[20];

    float* logits = (float*)d_out;
    float* loss   = logits + (long)NM * NV;

    char* p = (char*)d_ws;
    float*          x      = (float*)p;          p += (long)NM * NE * 4;
    unsigned short* hbuf   = (unsigned short*)p; p += (long)NM * NE * 2;
    unsigned short* qkv    = (unsigned short*)p; p += (long)NM * NQKV * 2;
    unsigned short* att    = (unsigned short*)p; p += (long)NM * NE * 2;
    unsigned short* hid    = (unsigned short*)p; p += (long)NM * NFF * 2;
    unsigned short* vt     = (unsigned short*)p; p += (long)NB * NH * NHS * NT * 2;
    float*          nll    = (float*)p;          p += (long)NM * 4;
    float*          pmb    = (float*)p;          p += (long)NM * 512 * 4;
    float*          psb    = (float*)p;          p += (long)NM * 512 * 4;
    unsigned short* parts  = (unsigned short*)p; p += (long)4 * NM * NE * 2;   // bf16 split-K partials
    unsigned short* wqkvT6 = (unsigned short*)p; p += (long)NL * NQKV * NE * 2;
    unsigned short* wprojT6= (unsigned short*)p; p += (long)NL * NE * NE * 2;
    unsigned short* wprojC6= (unsigned short*)p; p += (long)NL * NE * NE * 2;
    unsigned short* weffT6 = (unsigned short*)p; p += (long)NL * NE * NE * 2;
    float*          beff6  = (float*)p;          p += (long)NL * NE * 4;
    unsigned short* w1T6   = (unsigned short*)p; p += (long)NL * NFF * NE * 2;
    unsigned short* w2T6   = (unsigned short*)p; p += (long)NL * NE * NFF * 2;
    unsigned short* lmT    = (unsigned short*)p; p += (long)NV * NE * 2;

    dim3 blk(256);

    // ---- batched weight prep ----
    transpose4b_kernel<<<dim3(NE / 32, NE / 32, 4 * NL), blk, 0, stream>>>(
        wq, wk, wv, wproj, wqkvT6, wprojT6, wprojC6);
    transpose_ffn_kernel<<<dim3(NFF / 32, NE / 32, 2 * NL), blk, 0, stream>>>(w1, w2, w1T6, w2T6);
    gemm_weff_kernel<<<dim3(36, 1, NL), blk, 0, stream>>>(wprojT6, wprojC6, weffT6, 6, NE, NE);
    beff_b_kernel<<<dim3(NE, NL), blk, 0, stream>>>(bproj, wprojT6, beff6);
    transpose_cast_kernel<<<dim3(NV / 32, NE / 32), blk, 0, stream>>>(lm_w, lmT, NE, NV);

    // ---- embedding + LN1(0) ----
    embed_ln_kernel<<<NM, blk, 0, stream>>>(idx, tok, pos, ln1_g, ln1_b, x, hbuf);

    for (int l = 0; l < NL; ++l) {
        // QKV: direct bf16 output + fused V-transpose epilogue
        gemm_mfma<unsigned short, false, false, 1, true><<<dim3((NM/128)*(NQKV/128)), blk, 0, stream>>>(
            hbuf, wqkvT6 + (long)l * NQKV * NE, nullptr, qkv, vt, NM / 128, NQKV, NE);
        fattn_kernel<<<dim3(NT / 128, NB * NH), dim3(512), 0, stream>>>(qkv, vt, att);
        gemm_mfma<unsigned short, false, false, 2, false><<<dim3((NM/128)*(NE/128), 2), blk, 0, stream>>>(
            att, weffT6 + (long)l * NE * NE, nullptr, parts, nullptr, NM / 128, NE, NE);
        combine_ln_kernel<2><<<NM, blk, 0, stream>>>(
            parts, beff6 + (long)l * NE, x, ln2_g + (long)l * NE, ln2_b + (long)l * NE, hbuf);
        gemm_mfma<unsigned short, true, true, 1, false><<<dim3((NM/128)*(NFF/128)), blk, 0, stream>>>(
            hbuf, w1T6 + (long)l * NFF * NE, b1 + (long)l * NFF, hid, nullptr, NM / 128, NFF, NE);
        gemm_mfma<unsigned short, false, false, 4, false><<<dim3((NM/128)*(NE/128), 4), blk, 0, stream>>>(
            hid, w2T6 + (long)l * NE * NFF, nullptr, parts, nullptr, NM / 128, NE, NFF);
        const float* ng = (l < NL - 1) ? (ln1_g + (long)(l + 1) * NE) : lnf_g;
        const float* nb = (l < NL - 1) ? (ln1_b + (long)(l + 1) * NE) : lnf_b;
        combine_ln_kernel<4><<<NM, blk, 0, stream>>>(parts, b2 + (long)l * NE, x, ng, nb, hbuf);
    }

    // ---- LM head + fused LSE ----
    gemm256x128_lse<<<dim3((NM/256)*(NV/128)), dim3(512), 0, stream>>>(
        hbuf, lmT, lm_b, logits, pmb, psb, NM / 256, NV, NE);
    nll_combine_kernel<<<NM, blk, 0, stream>>>(logits, pmb, psb, targets, nll);
    loss_reduce_kernel<<<1, blk, 0, stream>>>(nll, loss);
}